// Round 1
// baseline (466.215 us; speedup 1.0000x reference)
//
#include <hip/hip_runtime.h>
#include <hip/hip_bf16.h>

// GAT 3-layer (PPI-style) on MI355X. fp32 tensors; edge_index (2,E) planar,
// int32/int64 via device flag. R10 -> R11:
// gemm_alpha8 was DS-pipe bound (2 LDS b32 reads per FMA; VALUBusy 32%).
// New gemm_alpha_rb: no LDS at all. 32 nodes register-blocked per wave
// (4 node-groups x 16 lanes x 4 cols); W rows streamed as coalesced float4
// (L1/L2-hot), X rows read via broadcast float4 (each row fetched once
// device-wide). 12 VMEM inst per 128 FMA inst -> VALU-bound.

__device__ __forceinline__ float lrelu(float s) { return (s >= 0.f) ? s : 0.2f * s; }

// ---------------- edge dtype detection: (2,E) planar ----------------

__global__ void detect_kernel(const int* __restrict__ ei, int* __restrict__ flag) {
    int t = threadIdx.x;  // 64 lanes
    int v = ei[2 * t + 1];
    unsigned long long b = __ballot(v == 0);
    if (t == 0) *flag = (b == ~0ULL) ? 1 : 0;
}

__device__ __forceinline__ int edge_at(const void* ei, int is64, long long idx) {
    return is64 ? (int)((const long long*)ei)[idx] : ((const int*)ei)[idx];
}

// ---------------- CSR build ----------------

__global__ void deg_init_kernel(int* __restrict__ deg, int N) {
    int t = blockIdx.x * blockDim.x + threadIdx.x;
    if (t < N) deg[t] = 1;  // self-loop
}

__global__ void deg_count_kernel(const void* __restrict__ ei, const int* __restrict__ flag,
                                 int* __restrict__ deg, int E) {
    int t = blockIdx.x * blockDim.x + threadIdx.x;
    if (t < E) {
        int dst = edge_at(ei, *flag, (long long)E + t);  // row 1 = dst
        atomicAdd(&deg[dst], 1);
    }
}

// 3-phase multi-block exclusive scan of deg[0..N) -> row_ptr/cursor.
__global__ __launch_bounds__(256)
void scanA_kernel(const int* __restrict__ deg, int* __restrict__ bsum, int N) {
    __shared__ int red[256];
    int t = threadIdx.x;
    int i = blockIdx.x * 256 + t;
    red[t] = (i < N) ? deg[i] : 0;
    __syncthreads();
#pragma unroll
    for (int off = 128; off > 0; off >>= 1) {
        if (t < off) red[t] += red[t + off];
        __syncthreads();
    }
    if (t == 0) bsum[blockIdx.x] = red[0];
}

__global__ __launch_bounds__(256)
void scanB_kernel(const int* __restrict__ bsum, int* __restrict__ boff,
                  int* __restrict__ row_ptrN, int nb) {
    __shared__ int s[256];
    int t = threadIdx.x;
    int v = (t < nb) ? bsum[t] : 0;
    s[t] = v;
    __syncthreads();
#pragma unroll
    for (int off = 1; off < 256; off <<= 1) {
        int u = (t >= off) ? s[t - off] : 0;
        __syncthreads();
        s[t] += u;
        __syncthreads();
    }
    if (t < nb) boff[t] = s[t] - v;  // exclusive
    if (t == nb - 1) *row_ptrN = s[t];
}

__global__ __launch_bounds__(256)
void scanC_kernel(const int* __restrict__ deg, const int* __restrict__ boff,
                  int* __restrict__ row_ptr, int* __restrict__ cursor, int N) {
    __shared__ int s[256];
    int t = threadIdx.x;
    int i = blockIdx.x * 256 + t;
    int v = (i < N) ? deg[i] : 0;
    s[t] = v;
    __syncthreads();
#pragma unroll
    for (int off = 1; off < 256; off <<= 1) {
        int u = (t >= off) ? s[t - off] : 0;
        __syncthreads();
        s[t] += u;
        __syncthreads();
    }
    if (i < N) {
        int ex = boff[blockIdx.x] + s[t] - v;
        row_ptr[i] = ex;
        cursor[i] = ex;
    }
}

__global__ void scatter_kernel(const void* __restrict__ ei, const int* __restrict__ flag,
                               int* __restrict__ cursor, int* __restrict__ adj, int E, int N) {
    int t = blockIdx.x * blockDim.x + threadIdx.x;
    if (t < E) {
        int is64 = *flag;
        int src = edge_at(ei, is64, t);
        int dst = edge_at(ei, is64, (long long)E + t);
        int pos = atomicAdd(&cursor[dst], 1);
        adj[pos] = src;
    } else if (t < E + N) {
        int n2 = t - E;
        int pos = atomicAdd(&cursor[n2], 1);
        adj[pos] = n2;  // self-loop
    }
}

// ---- w_as = W3 @ a3_src, w_ad = W3 @ a3_dst; and W3 padded to stride 244 ---

__global__ void w3a_kernel(const float* __restrict__ W3,
                           const float* __restrict__ a3s,
                           const float* __restrict__ a3d,
                           float* __restrict__ w_as, float* __restrict__ w_ad) {
    int t = threadIdx.x;  // 128 threads
    if (t >= 128) return;
    int k = t & 63;
    const float* a = (t < 64) ? a3s : a3d;
    float s = 0.f;
    for (int c = 0; c < 242; ++c) s = fmaf(W3[k * 242 + c], a[c], s);
    if (t < 64) w_as[k] = s; else w_ad[k] = s;
}

__global__ __launch_bounds__(256)
void w3pad_kernel(const float* __restrict__ W3, float* __restrict__ W3p) {
    int t = blockIdx.x * blockDim.x + threadIdx.x;  // 64*244
    if (t >= 64 * 244) return;
    int k = t / 244, c = t - k * 244;
    W3p[t] = (c < 242) ? W3[k * 242 + c] : 0.f;
}

// ---------------- GEMM + alpha (layers 1 & 2: 64 cols, H=8, C=8) -----------
// Register-blocked, no LDS. Per wave: 32 nodes. Lane layout: jj = lane>>4
// picks one of 4 node-subgroups (8 nodes each), cc = lane&15 picks a 4-col
// slice (16 lanes x 4 cols = 64 output cols). Per k-quad: 4 coalesced W
// float4 loads (L1/L2-hot) + 8 broadcast X float4 loads feed 128 FMA insts.
// Safe in-place (X==XW): each wave reads only its own nodes' rows, and all
// reads precede all writes in wave program order.

template <int K>
__global__ __launch_bounds__(256)
void gemm_alpha_rb(const float* __restrict__ X, const float* __restrict__ W,
                   const float* __restrict__ a_src, const float* __restrict__ a_dst,
                   float* __restrict__ XW, float* __restrict__ As, float* __restrict__ Ad,
                   int N) {
    int wave = threadIdx.x >> 6, lane = threadIdx.x & 63;
    int jj = lane >> 4, cc = lane & 15;
    int base = blockIdx.x * 128 + wave * 32 + jj * 8;

    const float* xr[8];
#pragma unroll
    for (int j = 0; j < 8; ++j) {
        int node = base + j;
        xr[j] = X + (size_t)(node < N ? node : 0) * K;
    }

    float4 o[8];
#pragma unroll
    for (int j = 0; j < 8; ++j) o[j] = make_float4(0.f, 0.f, 0.f, 0.f);

    const float* wp = W + cc * 4;
#pragma unroll 2
    for (int k = 0; k < K; k += 4) {
        float4 w0 = *(const float4*)(wp + (size_t)(k + 0) * 64);
        float4 w1 = *(const float4*)(wp + (size_t)(k + 1) * 64);
        float4 w2 = *(const float4*)(wp + (size_t)(k + 2) * 64);
        float4 w3 = *(const float4*)(wp + (size_t)(k + 3) * 64);
#pragma unroll
        for (int j = 0; j < 8; ++j) {
            float4 m = *(const float4*)(xr[j] + k);
            o[j].x = fmaf(m.x, w0.x, o[j].x);
            o[j].y = fmaf(m.x, w0.y, o[j].y);
            o[j].z = fmaf(m.x, w0.z, o[j].z);
            o[j].w = fmaf(m.x, w0.w, o[j].w);
            o[j].x = fmaf(m.y, w1.x, o[j].x);
            o[j].y = fmaf(m.y, w1.y, o[j].y);
            o[j].z = fmaf(m.y, w1.z, o[j].z);
            o[j].w = fmaf(m.y, w1.w, o[j].w);
            o[j].x = fmaf(m.z, w2.x, o[j].x);
            o[j].y = fmaf(m.z, w2.y, o[j].y);
            o[j].z = fmaf(m.z, w2.z, o[j].z);
            o[j].w = fmaf(m.z, w2.w, o[j].w);
            o[j].x = fmaf(m.w, w3.x, o[j].x);
            o[j].y = fmaf(m.w, w3.y, o[j].y);
            o[j].z = fmaf(m.w, w3.z, o[j].z);
            o[j].w = fmaf(m.w, w3.w, o[j].w);
        }
    }

    // epilogue: store xw + per-head alpha partials. Lane's 4 cols sit inside
    // head h = cc>>1; pair-reduce (cc even/odd) covers the 8 cols of the head.
    float4 av = *(const float4*)(a_src + cc * 4);
    float4 dv = *(const float4*)(a_dst + cc * 4);
#pragma unroll
    for (int j = 0; j < 8; ++j) {
        int node = base + j;
        if (node >= N) break;
        *(float4*)(XW + (size_t)node * 64 + cc * 4) = o[j];
        float s = o[j].x * av.x + o[j].y * av.y + o[j].z * av.z + o[j].w * av.w;
        float d = o[j].x * dv.x + o[j].y * dv.y + o[j].z * dv.z + o[j].w * dv.w;
        s += __shfl_xor(s, 1);
        d += __shfl_xor(d, 1);
        if ((cc & 1) == 0) {
            As[node * 8 + (cc >> 1)] = s;
            Ad[node * 8 + (cc >> 1)] = d;
        }
    }
}

// ---------------- Aggregation (layers 1 & 2): one wave per dst node --------

template <bool WITH_A3>
__global__ __launch_bounds__(256)
void agg_h8c8(const float* __restrict__ XW, const float* __restrict__ As,
              const float* __restrict__ Ad, const int* __restrict__ row_ptr,
              const int* __restrict__ adj, const float* __restrict__ bias,
              float* __restrict__ OUT,
              const float* __restrict__ w_as, const float* __restrict__ w_ad,
              float* __restrict__ As3, float* __restrict__ Ad3, int N) {
    int wave = threadIdx.x >> 6, lane = threadIdx.x & 63;
    int node = blockIdx.x * 4 + wave;
    if (node >= N) return;
    int beg = row_ptr[node], end = row_ptr[node + 1];
    int h = lane >> 3;
    float ad = Ad[node * 8 + h];

    float acc = 0.f, den = 0.f;
    int idx = beg;
    for (; idx + 8 <= end; idx += 8) {
        int s[8];
        float e[8], x[8];
#pragma unroll
        for (int k = 0; k < 8; ++k) s[k] = adj[idx + k];
#pragma unroll
        for (int k = 0; k < 8; ++k) e[k] = As[(size_t)s[k] * 8 + h];
#pragma unroll
        for (int k = 0; k < 8; ++k) x[k] = XW[(size_t)s[k] * 64 + lane];
#pragma unroll
        for (int k = 0; k < 8; ++k) {
            float p = __expf(lrelu(e[k] + ad));
            den += p;
            acc = fmaf(p, x[k], acc);
        }
    }
    for (; idx < end; ++idx) {
        int src = adj[idx];
        float p = __expf(lrelu(As[(size_t)src * 8 + h] + ad));
        den += p;
        acc = fmaf(p, XW[(size_t)src * 64 + lane], acc);
    }

    float v = fmaxf(acc / (den + 1e-16f) + bias[lane], 0.f);
    OUT[(size_t)node * 64 + lane] = v;

    if (WITH_A3) {
        float s3 = v * w_as[lane];
        float d3 = v * w_ad[lane];
#pragma unroll
        for (int m = 1; m <= 32; m <<= 1) {
            s3 += __shfl_xor(s3, m);
            d3 += __shfl_xor(d3, m);
        }
        if (lane == 0) {
            As3[node] = s3;
            Ad3[node] = d3;
        }
    }
}

// ---------------- Layer 3 aggregation in h-space (no LDS) ------------------

__global__ __launch_bounds__(256)
void agg3msg_kernel(const float* __restrict__ H2, const float* __restrict__ As3,
                    const float* __restrict__ Ad3, const int* __restrict__ row_ptr,
                    const int* __restrict__ adj, float* __restrict__ MSG, int N) {
    int wave = threadIdx.x >> 6, lane = threadIdx.x & 63;
    int node = blockIdx.x * 4 + wave;
    if (node >= N) return;
    int beg = row_ptr[node], end = row_ptr[node + 1];
    float ad = Ad3[node];

    float acc = 0.f, den = 0.f;
    int idx = beg;
    for (; idx + 8 <= end; idx += 8) {
        int s[8];
        float e[8], x[8];
#pragma unroll
        for (int k = 0; k < 8; ++k) s[k] = adj[idx + k];
#pragma unroll
        for (int k = 0; k < 8; ++k) e[k] = As3[s[k]];
#pragma unroll
        for (int k = 0; k < 8; ++k) x[k] = H2[(size_t)s[k] * 64 + lane];
#pragma unroll
        for (int k = 0; k < 8; ++k) {
            float p = __expf(lrelu(e[k] + ad));
            den += p;
            acc = fmaf(p, x[k], acc);
        }
    }
    for (; idx < end; ++idx) {
        int src = adj[idx];
        float p = __expf(lrelu(As3[src] + ad));
        den += p;
        acc = fmaf(p, H2[(size_t)src * 64 + lane], acc);
    }
    MSG[(size_t)node * 64 + lane] = acc / (den + 1e-16f);
}

// ---------------- gemm3 v2: OUT = softmax_pairs(relu(MSG @ W3 + b3)) -------
// 8 nodes register-blocked per wave (32/block); W3p (stride 244) streamed
// from global (L2-resident); only the 8KB MSG tile in LDS.

__global__ __launch_bounds__(256)
void gemm3_kernel(const float* __restrict__ MSG, const float* __restrict__ W3p,
                  const float* __restrict__ bias, float* __restrict__ OUT, int N) {
    __shared__ float msh[4][8][64];
    int wave = threadIdx.x >> 6, lane = threadIdx.x & 63;
    int base = blockIdx.x * 32 + wave * 8;

#pragma unroll
    for (int j = 0; j < 8; ++j) {
        int node = base + j;
        msh[wave][j][lane] = (node < N) ? MSG[(size_t)node * 64 + lane] : 0.f;
    }
    // same-wave LDS RAW: DS pipe in-order, compiler inserts lgkmcnt wait

    int c0 = lane * 4;  // lanes 0..60 carry channels; 61-63 idle
    if (c0 < 242) {
        float o[8][4];
#pragma unroll
        for (int j = 0; j < 8; ++j)
#pragma unroll
            for (int q = 0; q < 4; ++q) o[j][q] = 0.f;

#pragma unroll 4
        for (int k = 0; k < 64; k += 4) {
            float4 w0 = *(const float4*)(W3p + (size_t)(k + 0) * 244 + c0);
            float4 w1 = *(const float4*)(W3p + (size_t)(k + 1) * 244 + c0);
            float4 w2 = *(const float4*)(W3p + (size_t)(k + 2) * 244 + c0);
            float4 w3 = *(const float4*)(W3p + (size_t)(k + 3) * 244 + c0);
#pragma unroll
            for (int j = 0; j < 8; ++j) {
                float4 m = *(const float4*)(&msh[wave][j][k]);
                o[j][0] = fmaf(m.x, w0.x, o[j][0]);
                o[j][1] = fmaf(m.x, w0.y, o[j][1]);
                o[j][2] = fmaf(m.x, w0.z, o[j][2]);
                o[j][3] = fmaf(m.x, w0.w, o[j][3]);
                o[j][0] = fmaf(m.y, w1.x, o[j][0]);
                o[j][1] = fmaf(m.y, w1.y, o[j][1]);
                o[j][2] = fmaf(m.y, w1.z, o[j][2]);
                o[j][3] = fmaf(m.y, w1.w, o[j][3]);
                o[j][0] = fmaf(m.z, w2.x, o[j][0]);
                o[j][1] = fmaf(m.z, w2.y, o[j][1]);
                o[j][2] = fmaf(m.z, w2.z, o[j][2]);
                o[j][3] = fmaf(m.z, w2.w, o[j][3]);
                o[j][0] = fmaf(m.w, w3.x, o[j][0]);
                o[j][1] = fmaf(m.w, w3.y, o[j][1]);
                o[j][2] = fmaf(m.w, w3.z, o[j][2]);
                o[j][3] = fmaf(m.w, w3.w, o[j][3]);
            }
        }

        float b0 = bias[c0], b1v = bias[c0 + 1];
        float b2v = (c0 + 2 < 242) ? bias[c0 + 2] : 0.f;
        float b3v = (c0 + 3 < 242) ? bias[c0 + 3] : 0.f;
#pragma unroll
        for (int j = 0; j < 8; ++j) {
            int node = base + j;
            if (node >= N) break;
            size_t out_base = (size_t)node * 242 + c0;
            float v0 = fmaxf(o[j][0] + b0, 0.f);
            float v1 = fmaxf(o[j][1] + b1v, 0.f);
            float m01 = fmaxf(v0, v1);
            float e0 = __expf(v0 - m01), e1 = __expf(v1 - m01);
            float r01 = 1.f / (e0 + e1);
            OUT[out_base]     = e0 * r01;
            OUT[out_base + 1] = e1 * r01;
            if (c0 + 2 < 242) {
                float v2 = fmaxf(o[j][2] + b2v, 0.f);
                float v3 = fmaxf(o[j][3] + b3v, 0.f);
                float m23 = fmaxf(v2, v3);
                float e2 = __expf(v2 - m23), e3 = __expf(v3 - m23);
                float r23 = 1.f / (e2 + e3);
                OUT[out_base + 2] = e2 * r23;
                OUT[out_base + 3] = e3 * r23;
            }
        }
    }
}

// ---------------- launch ----------------

extern "C" void kernel_launch(void* const* d_in, const int* in_sizes, int n_in,
                              void* d_out, int out_size, void* d_ws, size_t ws_size,
                              hipStream_t stream) {
    const float* x   = (const float*)d_in[0];
    const void*  ei  = d_in[1];
    const float* W1  = (const float*)d_in[2];
    const float* a1s = (const float*)d_in[3];
    const float* a1d = (const float*)d_in[4];
    const float* b1  = (const float*)d_in[5];
    const float* W2  = (const float*)d_in[6];
    const float* a2s = (const float*)d_in[7];
    const float* a2d = (const float*)d_in[8];
    const float* b2  = (const float*)d_in[9];
    const float* W3  = (const float*)d_in[10];
    const float* a3s = (const float*)d_in[11];
    const float* a3d = (const float*)d_in[12];
    const float* b3  = (const float*)d_in[13];
    float* out = (float*)d_out;

    const int N = in_sizes[0] / 128;  // 50000
    const int E = in_sizes[1] / 2;    // 800000

    char* w = (char*)d_ws;
    auto alloc = [&](size_t bytes) {
        char* p = w;
        w += (bytes + 255) & ~(size_t)255;
        return p;
    };
    int*   flag    = (int*)alloc(4);
    int*   deg     = (int*)alloc((size_t)N * 4);
    int*   row_ptr = (int*)alloc(((size_t)N + 1) * 4);
    int*   cursor  = (int*)alloc((size_t)N * 4);
    int*   bsum    = (int*)alloc(256 * 4);
    int*   boff    = (int*)alloc(256 * 4);
    int*   adj     = (int*)alloc((size_t)(E + N) * 4);
    float* As      = (float*)alloc((size_t)N * 8 * 4);
    float* Ad      = (float*)alloc((size_t)N * 8 * 4);
    float* As3     = (float*)alloc((size_t)N * 4);
    float* Ad3     = (float*)alloc((size_t)N * 4);
    float* w_as    = (float*)alloc(64 * 4);
    float* w_ad    = (float*)alloc(64 * 4);
    float* W3p     = (float*)alloc((size_t)64 * 244 * 4);
    float* bufA    = (float*)alloc((size_t)N * 64 * 4);
    float* bufB    = (float*)alloc((size_t)N * 64 * 4);

    int nbs = (N + 255) / 256;  // 196 <= 256

    // CSR over dst (includes self-loops)
    detect_kernel<<<1, 64, 0, stream>>>((const int*)ei, flag);
    deg_init_kernel<<<nbs, 256, 0, stream>>>(deg, N);
    deg_count_kernel<<<(E + 255) / 256, 256, 0, stream>>>(ei, flag, deg, E);
    scanA_kernel<<<nbs, 256, 0, stream>>>(deg, bsum, N);
    scanB_kernel<<<1, 256, 0, stream>>>(bsum, boff, row_ptr + N, nbs);
    scanC_kernel<<<nbs, 256, 0, stream>>>(deg, boff, row_ptr, cursor, N);
    scatter_kernel<<<(E + N + 255) / 256, 256, 0, stream>>>(ei, flag, cursor, adj, E, N);
    w3a_kernel<<<1, 128, 0, stream>>>(W3, a3s, a3d, w_as, w_ad);
    w3pad_kernel<<<(64 * 244 + 255) / 256, 256, 0, stream>>>(W3, W3p);

    int nb4 = (N + 3) / 4;
    int nb128 = (N + 127) / 128;
    int nb32 = (N + 31) / 32;

    // Layer 1: x -> bufA (xw1), agg -> bufB (h1)
    gemm_alpha_rb<128><<<nb128, 256, 0, stream>>>(x, W1, a1s, a1d, bufA, As, Ad, N);
    agg_h8c8<false><<<nb4, 256, 0, stream>>>(bufA, As, Ad, row_ptr, adj, b1, bufB,
                                             nullptr, nullptr, nullptr, nullptr, N);
    // Layer 2: bufB -> bufB in-place (xw2), agg -> bufA (h2) + As3/Ad3 epilogue
    gemm_alpha_rb<64><<<nb128, 256, 0, stream>>>(bufB, W2, a2s, a2d, bufB, As, Ad, N);
    agg_h8c8<true><<<nb4, 256, 0, stream>>>(bufB, As, Ad, row_ptr, adj, b2, bufA,
                                            w_as, w_ad, As3, Ad3, N);
    // Layer 3: h-space aggregation (bufA -> bufB), then gemm3 v2 -> out
    agg3msg_kernel<<<nb4, 256, 0, stream>>>(bufA, As3, Ad3, row_ptr, adj, bufB, N);
    gemm3_kernel<<<nb32, 256, 0, stream>>>(bufB, W3p, b3, out, N);
}

// Round 2
// 449.153 us; speedup vs baseline: 1.0380x; 1.0380x over previous
//
#include <hip/hip_runtime.h>
#include <hip/hip_bf16.h>

// GAT 3-layer (PPI-style) on MI355X. fp32 tensors; edge_index (2,E) planar,
// int32/int64 via device flag. R11 -> R12:
// R11's 32-nodes/wave register-blocked GEMM starved occupancy (391 blocks ->
// 1.3 waves/SIMD, VALUBusy 9.5%, latency-bound). R12 keeps the no-LDS
// register blocking (which fixed the DS-pipe bound) but drops to 8 nodes/wave
// (2 per lane; 4 node-groups x 16 col-slices): grid 1563 blocks -> ~24
// waves/CU, ~48 VGPR. Per k-quad: 4 coalesced W float4 + 2 broadcast X float4
// feed 32 FMA insts.

__device__ __forceinline__ float lrelu(float s) { return (s >= 0.f) ? s : 0.2f * s; }

// ---------------- edge dtype detection: (2,E) planar ----------------

__global__ void detect_kernel(const int* __restrict__ ei, int* __restrict__ flag) {
    int t = threadIdx.x;  // 64 lanes
    int v = ei[2 * t + 1];
    unsigned long long b = __ballot(v == 0);
    if (t == 0) *flag = (b == ~0ULL) ? 1 : 0;
}

__device__ __forceinline__ int edge_at(const void* ei, int is64, long long idx) {
    return is64 ? (int)((const long long*)ei)[idx] : ((const int*)ei)[idx];
}

// ---------------- CSR build ----------------

__global__ void deg_init_kernel(int* __restrict__ deg, int N) {
    int t = blockIdx.x * blockDim.x + threadIdx.x;
    if (t < N) deg[t] = 1;  // self-loop
}

__global__ void deg_count_kernel(const void* __restrict__ ei, const int* __restrict__ flag,
                                 int* __restrict__ deg, int E) {
    int t = blockIdx.x * blockDim.x + threadIdx.x;
    if (t < E) {
        int dst = edge_at(ei, *flag, (long long)E + t);  // row 1 = dst
        atomicAdd(&deg[dst], 1);
    }
}

// 3-phase multi-block exclusive scan of deg[0..N) -> row_ptr/cursor.
__global__ __launch_bounds__(256)
void scanA_kernel(const int* __restrict__ deg, int* __restrict__ bsum, int N) {
    __shared__ int red[256];
    int t = threadIdx.x;
    int i = blockIdx.x * 256 + t;
    red[t] = (i < N) ? deg[i] : 0;
    __syncthreads();
#pragma unroll
    for (int off = 128; off > 0; off >>= 1) {
        if (t < off) red[t] += red[t + off];
        __syncthreads();
    }
    if (t == 0) bsum[blockIdx.x] = red[0];
}

__global__ __launch_bounds__(256)
void scanB_kernel(const int* __restrict__ bsum, int* __restrict__ boff,
                  int* __restrict__ row_ptrN, int nb) {
    __shared__ int s[256];
    int t = threadIdx.x;
    int v = (t < nb) ? bsum[t] : 0;
    s[t] = v;
    __syncthreads();
#pragma unroll
    for (int off = 1; off < 256; off <<= 1) {
        int u = (t >= off) ? s[t - off] : 0;
        __syncthreads();
        s[t] += u;
        __syncthreads();
    }
    if (t < nb) boff[t] = s[t] - v;  // exclusive
    if (t == nb - 1) *row_ptrN = s[t];
}

__global__ __launch_bounds__(256)
void scanC_kernel(const int* __restrict__ deg, const int* __restrict__ boff,
                  int* __restrict__ row_ptr, int* __restrict__ cursor, int N) {
    __shared__ int s[256];
    int t = threadIdx.x;
    int i = blockIdx.x * 256 + t;
    int v = (i < N) ? deg[i] : 0;
    s[t] = v;
    __syncthreads();
#pragma unroll
    for (int off = 1; off < 256; off <<= 1) {
        int u = (t >= off) ? s[t - off] : 0;
        __syncthreads();
        s[t] += u;
        __syncthreads();
    }
    if (i < N) {
        int ex = boff[blockIdx.x] + s[t] - v;
        row_ptr[i] = ex;
        cursor[i] = ex;
    }
}

__global__ void scatter_kernel(const void* __restrict__ ei, const int* __restrict__ flag,
                               int* __restrict__ cursor, int* __restrict__ adj, int E, int N) {
    int t = blockIdx.x * blockDim.x + threadIdx.x;
    if (t < E) {
        int is64 = *flag;
        int src = edge_at(ei, is64, t);
        int dst = edge_at(ei, is64, (long long)E + t);
        int pos = atomicAdd(&cursor[dst], 1);
        adj[pos] = src;
    } else if (t < E + N) {
        int n2 = t - E;
        int pos = atomicAdd(&cursor[n2], 1);
        adj[pos] = n2;  // self-loop
    }
}

// ---- w_as = W3 @ a3_src, w_ad = W3 @ a3_dst; and W3 padded to stride 244 ---

__global__ void w3a_kernel(const float* __restrict__ W3,
                           const float* __restrict__ a3s,
                           const float* __restrict__ a3d,
                           float* __restrict__ w_as, float* __restrict__ w_ad) {
    int t = threadIdx.x;  // 128 threads
    if (t >= 128) return;
    int k = t & 63;
    const float* a = (t < 64) ? a3s : a3d;
    float s = 0.f;
    for (int c = 0; c < 242; ++c) s = fmaf(W3[k * 242 + c], a[c], s);
    if (t < 64) w_as[k] = s; else w_ad[k] = s;
}

__global__ __launch_bounds__(256)
void w3pad_kernel(const float* __restrict__ W3, float* __restrict__ W3p) {
    int t = blockIdx.x * blockDim.x + threadIdx.x;  // 64*244
    if (t >= 64 * 244) return;
    int k = t / 244, c = t - k * 244;
    W3p[t] = (c < 242) ? W3[k * 242 + c] : 0.f;
}

// ---------------- GEMM + alpha (layers 1 & 2: 64 cols, H=8, C=8) -----------
// Register-blocked, no LDS, 8 nodes per wave (2 per lane). Lane layout:
// jj = lane>>4 picks one of 4 node-pairs, cc = lane&15 picks a 4-col slice
// (16 lanes x 4 cols = 64 output cols). Per k-quad: 4 coalesced W float4
// loads (dedup'd across jj groups) + 2 broadcast X float4 loads feed 32 FMA
// insts. Grid = N/32 blocks -> ~6 blocks/CU -> latency hidden by TLP.
// Safe in-place (X==XW): each lane reads only its own nodes' rows and all
// reads are consumed before the dependent stores issue.

template <int K>
__global__ __launch_bounds__(256)
void gemm_alpha_v3(const float* __restrict__ X, const float* __restrict__ W,
                   const float* __restrict__ a_src, const float* __restrict__ a_dst,
                   float* __restrict__ XW, float* __restrict__ As, float* __restrict__ Ad,
                   int N) {
    int wave = threadIdx.x >> 6, lane = threadIdx.x & 63;
    int jj = lane >> 4, cc = lane & 15;
    int base = blockIdx.x * 32 + wave * 8 + jj * 2;

    int n0 = (base < N) ? base : N - 1;
    int n1 = (base + 1 < N) ? base + 1 : N - 1;
    const float* x0 = X + (size_t)n0 * K;
    const float* x1 = X + (size_t)n1 * K;

    float4 o0 = make_float4(0.f, 0.f, 0.f, 0.f);
    float4 o1 = make_float4(0.f, 0.f, 0.f, 0.f);

    const float* wp = W + cc * 4;
#pragma unroll 4
    for (int k = 0; k < K; k += 4) {
        float4 w0 = *(const float4*)(wp + (size_t)(k + 0) * 64);
        float4 w1 = *(const float4*)(wp + (size_t)(k + 1) * 64);
        float4 w2 = *(const float4*)(wp + (size_t)(k + 2) * 64);
        float4 w3 = *(const float4*)(wp + (size_t)(k + 3) * 64);
        float4 m0 = *(const float4*)(x0 + k);
        float4 m1 = *(const float4*)(x1 + k);

        o0.x = fmaf(m0.x, w0.x, o0.x);
        o0.y = fmaf(m0.x, w0.y, o0.y);
        o0.z = fmaf(m0.x, w0.z, o0.z);
        o0.w = fmaf(m0.x, w0.w, o0.w);
        o0.x = fmaf(m0.y, w1.x, o0.x);
        o0.y = fmaf(m0.y, w1.y, o0.y);
        o0.z = fmaf(m0.y, w1.z, o0.z);
        o0.w = fmaf(m0.y, w1.w, o0.w);
        o0.x = fmaf(m0.z, w2.x, o0.x);
        o0.y = fmaf(m0.z, w2.y, o0.y);
        o0.z = fmaf(m0.z, w2.z, o0.z);
        o0.w = fmaf(m0.z, w2.w, o0.w);
        o0.x = fmaf(m0.w, w3.x, o0.x);
        o0.y = fmaf(m0.w, w3.y, o0.y);
        o0.z = fmaf(m0.w, w3.z, o0.z);
        o0.w = fmaf(m0.w, w3.w, o0.w);

        o1.x = fmaf(m1.x, w0.x, o1.x);
        o1.y = fmaf(m1.x, w0.y, o1.y);
        o1.z = fmaf(m1.x, w0.z, o1.z);
        o1.w = fmaf(m1.x, w0.w, o1.w);
        o1.x = fmaf(m1.y, w1.x, o1.x);
        o1.y = fmaf(m1.y, w1.y, o1.y);
        o1.z = fmaf(m1.y, w1.z, o1.z);
        o1.w = fmaf(m1.y, w1.w, o1.w);
        o1.x = fmaf(m1.z, w2.x, o1.x);
        o1.y = fmaf(m1.z, w2.y, o1.y);
        o1.z = fmaf(m1.z, w2.z, o1.z);
        o1.w = fmaf(m1.z, w2.w, o1.w);
        o1.x = fmaf(m1.w, w3.x, o1.x);
        o1.y = fmaf(m1.w, w3.y, o1.y);
        o1.z = fmaf(m1.w, w3.z, o1.z);
        o1.w = fmaf(m1.w, w3.w, o1.w);
    }

    // epilogue: store xw + per-head alpha partials. Lane's 4 cols sit inside
    // head h = cc>>1; pair-reduce (cc even/odd) covers the 8 cols of the head.
    // Node-valid predicates are uniform across the reducing lane pair.
    float4 av = *(const float4*)(a_src + cc * 4);
    float4 dv = *(const float4*)(a_dst + cc * 4);

    if (base < N) {
        *(float4*)(XW + (size_t)base * 64 + cc * 4) = o0;
        float s = o0.x * av.x + o0.y * av.y + o0.z * av.z + o0.w * av.w;
        float d = o0.x * dv.x + o0.y * dv.y + o0.z * dv.z + o0.w * dv.w;
        s += __shfl_xor(s, 1);
        d += __shfl_xor(d, 1);
        if ((cc & 1) == 0) {
            As[base * 8 + (cc >> 1)] = s;
            Ad[base * 8 + (cc >> 1)] = d;
        }
    }
    if (base + 1 < N) {
        *(float4*)(XW + (size_t)(base + 1) * 64 + cc * 4) = o1;
        float s = o1.x * av.x + o1.y * av.y + o1.z * av.z + o1.w * av.w;
        float d = o1.x * dv.x + o1.y * dv.y + o1.z * dv.z + o1.w * dv.w;
        s += __shfl_xor(s, 1);
        d += __shfl_xor(d, 1);
        if ((cc & 1) == 0) {
            As[(base + 1) * 8 + (cc >> 1)] = s;
            Ad[(base + 1) * 8 + (cc >> 1)] = d;
        }
    }
}

// ---------------- Aggregation (layers 1 & 2): one wave per dst node --------

template <bool WITH_A3>
__global__ __launch_bounds__(256)
void agg_h8c8(const float* __restrict__ XW, const float* __restrict__ As,
              const float* __restrict__ Ad, const int* __restrict__ row_ptr,
              const int* __restrict__ adj, const float* __restrict__ bias,
              float* __restrict__ OUT,
              const float* __restrict__ w_as, const float* __restrict__ w_ad,
              float* __restrict__ As3, float* __restrict__ Ad3, int N) {
    int wave = threadIdx.x >> 6, lane = threadIdx.x & 63;
    int node = blockIdx.x * 4 + wave;
    if (node >= N) return;
    int beg = row_ptr[node], end = row_ptr[node + 1];
    int h = lane >> 3;
    float ad = Ad[node * 8 + h];

    float acc = 0.f, den = 0.f;
    int idx = beg;
    for (; idx + 8 <= end; idx += 8) {
        int s[8];
        float e[8], x[8];
#pragma unroll
        for (int k = 0; k < 8; ++k) s[k] = adj[idx + k];
#pragma unroll
        for (int k = 0; k < 8; ++k) e[k] = As[(size_t)s[k] * 8 + h];
#pragma unroll
        for (int k = 0; k < 8; ++k) x[k] = XW[(size_t)s[k] * 64 + lane];
#pragma unroll
        for (int k = 0; k < 8; ++k) {
            float p = __expf(lrelu(e[k] + ad));
            den += p;
            acc = fmaf(p, x[k], acc);
        }
    }
    for (; idx < end; ++idx) {
        int src = adj[idx];
        float p = __expf(lrelu(As[(size_t)src * 8 + h] + ad));
        den += p;
        acc = fmaf(p, XW[(size_t)src * 64 + lane], acc);
    }

    float v = fmaxf(acc / (den + 1e-16f) + bias[lane], 0.f);
    OUT[(size_t)node * 64 + lane] = v;

    if (WITH_A3) {
        float s3 = v * w_as[lane];
        float d3 = v * w_ad[lane];
#pragma unroll
        for (int m = 1; m <= 32; m <<= 1) {
            s3 += __shfl_xor(s3, m);
            d3 += __shfl_xor(d3, m);
        }
        if (lane == 0) {
            As3[node] = s3;
            Ad3[node] = d3;
        }
    }
}

// ---------------- Layer 3 aggregation in h-space (no LDS) ------------------

__global__ __launch_bounds__(256)
void agg3msg_kernel(const float* __restrict__ H2, const float* __restrict__ As3,
                    const float* __restrict__ Ad3, const int* __restrict__ row_ptr,
                    const int* __restrict__ adj, float* __restrict__ MSG, int N) {
    int wave = threadIdx.x >> 6, lane = threadIdx.x & 63;
    int node = blockIdx.x * 4 + wave;
    if (node >= N) return;
    int beg = row_ptr[node], end = row_ptr[node + 1];
    float ad = Ad3[node];

    float acc = 0.f, den = 0.f;
    int idx = beg;
    for (; idx + 8 <= end; idx += 8) {
        int s[8];
        float e[8], x[8];
#pragma unroll
        for (int k = 0; k < 8; ++k) s[k] = adj[idx + k];
#pragma unroll
        for (int k = 0; k < 8; ++k) e[k] = As3[s[k]];
#pragma unroll
        for (int k = 0; k < 8; ++k) x[k] = H2[(size_t)s[k] * 64 + lane];
#pragma unroll
        for (int k = 0; k < 8; ++k) {
            float p = __expf(lrelu(e[k] + ad));
            den += p;
            acc = fmaf(p, x[k], acc);
        }
    }
    for (; idx < end; ++idx) {
        int src = adj[idx];
        float p = __expf(lrelu(As3[src] + ad));
        den += p;
        acc = fmaf(p, H2[(size_t)src * 64 + lane], acc);
    }
    MSG[(size_t)node * 64 + lane] = acc / (den + 1e-16f);
}

// ---------------- gemm3 v2: OUT = softmax_pairs(relu(MSG @ W3 + b3)) -------
// 8 nodes register-blocked per wave (32/block); W3p (stride 244) streamed
// from global (L2-resident); only the 8KB MSG tile in LDS.

__global__ __launch_bounds__(256)
void gemm3_kernel(const float* __restrict__ MSG, const float* __restrict__ W3p,
                  const float* __restrict__ bias, float* __restrict__ OUT, int N) {
    __shared__ float msh[4][8][64];
    int wave = threadIdx.x >> 6, lane = threadIdx.x & 63;
    int base = blockIdx.x * 32 + wave * 8;

#pragma unroll
    for (int j = 0; j < 8; ++j) {
        int node = base + j;
        msh[wave][j][lane] = (node < N) ? MSG[(size_t)node * 64 + lane] : 0.f;
    }
    // same-wave LDS RAW: DS pipe in-order, compiler inserts lgkmcnt wait

    int c0 = lane * 4;  // lanes 0..60 carry channels; 61-63 idle
    if (c0 < 242) {
        float o[8][4];
#pragma unroll
        for (int j = 0; j < 8; ++j)
#pragma unroll
            for (int q = 0; q < 4; ++q) o[j][q] = 0.f;

#pragma unroll 4
        for (int k = 0; k < 64; k += 4) {
            float4 w0 = *(const float4*)(W3p + (size_t)(k + 0) * 244 + c0);
            float4 w1 = *(const float4*)(W3p + (size_t)(k + 1) * 244 + c0);
            float4 w2 = *(const float4*)(W3p + (size_t)(k + 2) * 244 + c0);
            float4 w3 = *(const float4*)(W3p + (size_t)(k + 3) * 244 + c0);
#pragma unroll
            for (int j = 0; j < 8; ++j) {
                float4 m = *(const float4*)(&msh[wave][j][k]);
                o[j][0] = fmaf(m.x, w0.x, o[j][0]);
                o[j][1] = fmaf(m.x, w0.y, o[j][1]);
                o[j][2] = fmaf(m.x, w0.z, o[j][2]);
                o[j][3] = fmaf(m.x, w0.w, o[j][3]);
                o[j][0] = fmaf(m.y, w1.x, o[j][0]);
                o[j][1] = fmaf(m.y, w1.y, o[j][1]);
                o[j][2] = fmaf(m.y, w1.z, o[j][2]);
                o[j][3] = fmaf(m.y, w1.w, o[j][3]);
                o[j][0] = fmaf(m.z, w2.x, o[j][0]);
                o[j][1] = fmaf(m.z, w2.y, o[j][1]);
                o[j][2] = fmaf(m.z, w2.z, o[j][2]);
                o[j][3] = fmaf(m.z, w2.w, o[j][3]);
                o[j][0] = fmaf(m.w, w3.x, o[j][0]);
                o[j][1] = fmaf(m.w, w3.y, o[j][1]);
                o[j][2] = fmaf(m.w, w3.z, o[j][2]);
                o[j][3] = fmaf(m.w, w3.w, o[j][3]);
            }
        }

        float b0 = bias[c0], b1v = bias[c0 + 1];
        float b2v = (c0 + 2 < 242) ? bias[c0 + 2] : 0.f;
        float b3v = (c0 + 3 < 242) ? bias[c0 + 3] : 0.f;
#pragma unroll
        for (int j = 0; j < 8; ++j) {
            int node = base + j;
            if (node >= N) break;
            size_t out_base = (size_t)node * 242 + c0;
            float v0 = fmaxf(o[j][0] + b0, 0.f);
            float v1 = fmaxf(o[j][1] + b1v, 0.f);
            float m01 = fmaxf(v0, v1);
            float e0 = __expf(v0 - m01), e1 = __expf(v1 - m01);
            float r01 = 1.f / (e0 + e1);
            OUT[out_base]     = e0 * r01;
            OUT[out_base + 1] = e1 * r01;
            if (c0 + 2 < 242) {
                float v2 = fmaxf(o[j][2] + b2v, 0.f);
                float v3 = fmaxf(o[j][3] + b3v, 0.f);
                float m23 = fmaxf(v2, v3);
                float e2 = __expf(v2 - m23), e3 = __expf(v3 - m23);
                float r23 = 1.f / (e2 + e3);
                OUT[out_base + 2] = e2 * r23;
                OUT[out_base + 3] = e3 * r23;
            }
        }
    }
}

// ---------------- launch ----------------

extern "C" void kernel_launch(void* const* d_in, const int* in_sizes, int n_in,
                              void* d_out, int out_size, void* d_ws, size_t ws_size,
                              hipStream_t stream) {
    const float* x   = (const float*)d_in[0];
    const void*  ei  = d_in[1];
    const float* W1  = (const float*)d_in[2];
    const float* a1s = (const float*)d_in[3];
    const float* a1d = (const float*)d_in[4];
    const float* b1  = (const float*)d_in[5];
    const float* W2  = (const float*)d_in[6];
    const float* a2s = (const float*)d_in[7];
    const float* a2d = (const float*)d_in[8];
    const float* b2  = (const float*)d_in[9];
    const float* W3  = (const float*)d_in[10];
    const float* a3s = (const float*)d_in[11];
    const float* a3d = (const float*)d_in[12];
    const float* b3  = (const float*)d_in[13];
    float* out = (float*)d_out;

    const int N = in_sizes[0] / 128;  // 50000
    const int E = in_sizes[1] / 2;    // 800000

    char* w = (char*)d_ws;
    auto alloc = [&](size_t bytes) {
        char* p = w;
        w += (bytes + 255) & ~(size_t)255;
        return p;
    };
    int*   flag    = (int*)alloc(4);
    int*   deg     = (int*)alloc((size_t)N * 4);
    int*   row_ptr = (int*)alloc(((size_t)N + 1) * 4);
    int*   cursor  = (int*)alloc((size_t)N * 4);
    int*   bsum    = (int*)alloc(256 * 4);
    int*   boff    = (int*)alloc(256 * 4);
    int*   adj     = (int*)alloc((size_t)(E + N) * 4);
    float* As      = (float*)alloc((size_t)N * 8 * 4);
    float* Ad      = (float*)alloc((size_t)N * 8 * 4);
    float* As3     = (float*)alloc((size_t)N * 4);
    float* Ad3     = (float*)alloc((size_t)N * 4);
    float* w_as    = (float*)alloc(64 * 4);
    float* w_ad    = (float*)alloc(64 * 4);
    float* W3p     = (float*)alloc((size_t)64 * 244 * 4);
    float* bufA    = (float*)alloc((size_t)N * 64 * 4);
    float* bufB    = (float*)alloc((size_t)N * 64 * 4);

    int nbs = (N + 255) / 256;  // 196 <= 256

    // CSR over dst (includes self-loops)
    detect_kernel<<<1, 64, 0, stream>>>((const int*)ei, flag);
    deg_init_kernel<<<nbs, 256, 0, stream>>>(deg, N);
    deg_count_kernel<<<(E + 255) / 256, 256, 0, stream>>>(ei, flag, deg, E);
    scanA_kernel<<<nbs, 256, 0, stream>>>(deg, bsum, N);
    scanB_kernel<<<1, 256, 0, stream>>>(bsum, boff, row_ptr + N, nbs);
    scanC_kernel<<<nbs, 256, 0, stream>>>(deg, boff, row_ptr, cursor, N);
    scatter_kernel<<<(E + N + 255) / 256, 256, 0, stream>>>(ei, flag, cursor, adj, E, N);
    w3a_kernel<<<1, 128, 0, stream>>>(W3, a3s, a3d, w_as, w_ad);
    w3pad_kernel<<<(64 * 244 + 255) / 256, 256, 0, stream>>>(W3, W3p);

    int nb4 = (N + 3) / 4;
    int nb32 = (N + 31) / 32;

    // Layer 1: x -> bufA (xw1), agg -> bufB (h1)
    gemm_alpha_v3<128><<<nb32, 256, 0, stream>>>(x, W1, a1s, a1d, bufA, As, Ad, N);
    agg_h8c8<false><<<nb4, 256, 0, stream>>>(bufA, As, Ad, row_ptr, adj, b1, bufB,
                                             nullptr, nullptr, nullptr, nullptr, N);
    // Layer 2: bufB -> bufB in-place (xw2), agg -> bufA (h2) + As3/Ad3 epilogue
    gemm_alpha_v3<64><<<nb32, 256, 0, stream>>>(bufB, W2, a2s, a2d, bufB, As, Ad, N);
    agg_h8c8<true><<<nb4, 256, 0, stream>>>(bufB, As, Ad, row_ptr, adj, b2, bufA,
                                            w_as, w_ad, As3, Ad3, N);
    // Layer 3: h-space aggregation (bufA -> bufB), then gemm3 v2 -> out
    agg3msg_kernel<<<nb4, 256, 0, stream>>>(bufA, As3, Ad3, row_ptr, adj, bufB, N);
    gemm3_kernel<<<nb32, 256, 0, stream>>>(bufB, W3p, b3, out, N);
}

// Round 4
// 385.551 us; speedup vs baseline: 1.2092x; 1.1650x over previous
//
#include <hip/hip_runtime.h>
#include <hip/hip_bf16.h>

// GAT 3-layer (PPI-style) on MI355X. fp32 tensors; edge_index (2,E) planar,
// int32/int64 via device flag. R13 retry:
// scatter_kernel wrote 54.7MB HBM for a 3.4MB adj (every random 4B store =
// one 64B line). Replaced the CSR build with a bucketed counting sort:
//   histA  - LDS hist over 196 dst-buckets (256 nodes each)
//   scans  - bucket bases + per-(block,bucket) run offsets
//   partC  - LDS-staged partition; writes (src,dst) as contiguous runs
//   csrD   - per-bucket local CSR in LDS; row_ptr direct; adj written as one
//            contiguous stream per bucket
// All HBM writes coalesced; zero global atomics in the build.
// vs failed R13: (a) blkhist/blkoff/part all aliased into bufA so total
// workspace (32.86MB) is strictly below the proven R12 footprint (33.27MB);
// (b) every LDS bucket index masked &255 so OOB is impossible even under
// dtype mis-detection.

#define CH 4096     // items per partition block
#define CAP 8192    // csrD staging capacity (mean bucket = 4352, 60 sigma headroom)

__device__ __forceinline__ float lrelu(float s) { return (s >= 0.f) ? s : 0.2f * s; }

// ---------------- edge dtype detection: (2,E) planar ----------------

__global__ void detect_kernel(const int* __restrict__ ei, int* __restrict__ flag) {
    int t = threadIdx.x;  // 64 lanes
    int v = ei[2 * t + 1];
    unsigned long long b = __ballot(v == 0);
    if (t == 0) *flag = (b == ~0ULL) ? 1 : 0;
}

__device__ __forceinline__ int edge_at(const void* ei, int is64, long long idx) {
    return is64 ? (int)((const long long*)ei)[idx] : ((const int*)ei)[idx];
}

// ---------------- bucketed CSR build ----------------

__global__ void zero_btot_kernel(int* __restrict__ btot) {
    btot[threadIdx.x] = 0;  // 256 threads
}

// Per-block bucket histogram. Item t in [0,E) = edge t (dst row), [E,E+N) =
// self-loop (dst = t-E). blkhist[bucket*256 + blk], btot[bucket].
__global__ __launch_bounds__(256)
void histA_kernel(const void* __restrict__ ei, const int* __restrict__ flag,
                  int* __restrict__ blkhist, int* __restrict__ btot, int E, int N) {
    __shared__ int h[256];
    int t = threadIdx.x;
    h[t] = 0;
    __syncthreads();
    int is64 = *flag;
    long long base = (long long)blockIdx.x * CH;
    long long tot = (long long)E + N;
#pragma unroll
    for (int i = 0; i < CH / 256; ++i) {
        long long idx = base + t + i * 256;
        if (idx < tot) {
            int dst = (idx < E) ? edge_at(ei, is64, (long long)E + idx) : (int)(idx - E);
            atomicAdd(&h[(dst >> 8) & 255], 1);
        }
    }
    __syncthreads();
    int nb = (N + 255) >> 8;
    if (t < nb) {
        blkhist[t * 256 + blockIdx.x] = h[t];
        atomicAdd(&btot[t], h[t]);
    }
}

// Exclusive scan over bucket totals -> bbase[0..nb], bbase[nb] = total.
__global__ __launch_bounds__(256)
void bucket_scan_kernel(const int* __restrict__ btot, int* __restrict__ bbase,
                        int nb, int total) {
    __shared__ int s[256];
    int t = threadIdx.x;
    int v = (t < nb) ? btot[t] : 0;
    s[t] = v;
    __syncthreads();
#pragma unroll
    for (int off = 1; off < 256; off <<= 1) {
        int u = (t >= off) ? s[t - off] : 0;
        __syncthreads();
        s[t] += u;
        __syncthreads();
    }
    if (t < nb) bbase[t] = s[t] - v;
    if (t == 0) bbase[nb] = total;
}

// Per-bucket exclusive scan across blocks -> absolute run base blkoff.
__global__ __launch_bounds__(256)
void blk_scan_kernel(const int* __restrict__ blkhist, const int* __restrict__ bbase,
                     int* __restrict__ blkoff, int nblk) {
    __shared__ int s[256];
    int t = threadIdx.x;
    int b = blockIdx.x;
    int v = (t < nblk) ? blkhist[b * 256 + t] : 0;
    s[t] = v;
    __syncthreads();
#pragma unroll
    for (int off = 1; off < 256; off <<= 1) {
        int u = (t >= off) ? s[t - off] : 0;
        __syncthreads();
        s[t] += u;
        __syncthreads();
    }
    if (t < nblk) blkoff[b * 256 + t] = bbase[b] + s[t] - v;
}

// Partition: stage the block's CH items in LDS sorted by bucket, then write
// each bucket run contiguously (consecutive lanes -> consecutive addresses).
__global__ __launch_bounds__(256)
void partC_kernel(const void* __restrict__ ei, const int* __restrict__ flag,
                  const int* __restrict__ blkoff, int2* __restrict__ part,
                  int E, int N) {
    __shared__ int h[256];
    __shared__ int lst[256];
    __shared__ int cur[256];
    __shared__ int grb[256];
    __shared__ int ssrc[CH];
    __shared__ int sdst[CH];
    int t = threadIdx.x;
    h[t] = 0;
    __syncthreads();
    int is64 = *flag;
    long long base = (long long)blockIdx.x * CH;
    long long tot = (long long)E + N;
    int msrc[CH / 256], mdst[CH / 256], mb[CH / 256];
#pragma unroll
    for (int i = 0; i < CH / 256; ++i) {
        long long idx = base + t + i * 256;
        if (idx < tot) {
            int s, d;
            if (idx < E) {
                s = edge_at(ei, is64, idx);
                d = edge_at(ei, is64, (long long)E + idx);
            } else {
                s = (int)(idx - E);
                d = s;
            }
            msrc[i] = s;
            mdst[i] = d;
            mb[i] = (d >> 8) & 255;
            atomicAdd(&h[mb[i]], 1);
        } else {
            mb[i] = -1;
        }
    }
    __syncthreads();
    // exclusive scan of h -> lst; cur = lst; grb = absolute run base
    int v = h[t];
    lst[t] = v;
    __syncthreads();
#pragma unroll
    for (int off = 1; off < 256; off <<= 1) {
        int u = (t >= off) ? lst[t - off] : 0;
        __syncthreads();
        lst[t] += u;
        __syncthreads();
    }
    int ex = lst[t] - v;   // each thread touches only its own slot here
    lst[t] = ex;
    cur[t] = ex;
    int nb = (N + 255) >> 8;
    grb[t] = (t < nb) ? blkoff[t * 256 + blockIdx.x] : 0;
    __syncthreads();
#pragma unroll
    for (int i = 0; i < CH / 256; ++i) {
        if (mb[i] >= 0) {
            int slot = atomicAdd(&cur[mb[i]], 1);
            ssrc[slot] = msrc[i];
            sdst[slot] = mdst[i];
        }
    }
    __syncthreads();
    int items = (int)((tot - base < CH) ? (tot - base) : CH);
    for (int r = t; r < items; r += 256) {
        int d = sdst[r];
        int b = (d >> 8) & 255;
        part[grb[b] + (r - lst[b])] = make_int2(ssrc[r], d);
    }
}

// Per-bucket local CSR: counts -> scan -> row_ptr; stage srcs in final order
// in LDS; write the bucket's adj region as one contiguous stream.
__global__ __launch_bounds__(256)
void csrD_kernel(const int2* __restrict__ part, const int* __restrict__ bbase,
                 int* __restrict__ row_ptr, int* __restrict__ adj, int N) {
    __shared__ int cnt[256];
    __shared__ int lst[256];
    __shared__ int cur[256];
    __shared__ int ssrc[CAP];
    int t = threadIdx.x;
    int b = blockIdx.x;
    int lo = bbase[b], hi = bbase[b + 1];
    int n0 = b << 8;
    cnt[t] = 0;
    __syncthreads();
    for (int r = lo + t; r < hi; r += 256) atomicAdd(&cnt[part[r].y & 255], 1);
    __syncthreads();
    int v = cnt[t];
    lst[t] = v;
    __syncthreads();
#pragma unroll
    for (int off = 1; off < 256; off <<= 1) {
        int u = (t >= off) ? lst[t - off] : 0;
        __syncthreads();
        lst[t] += u;
        __syncthreads();
    }
    int ex = lst[t] - v;
    lst[t] = ex;
    cur[t] = ex;
    __syncthreads();
    if (n0 + t < N) row_ptr[n0 + t] = lo + ex;
    if (b == gridDim.x - 1 && t == 0) row_ptr[N] = hi;
    int items = hi - lo;
    if (items <= CAP) {
        for (int r = lo + t; r < hi; r += 256) {
            int2 p = part[r];
            int slot = atomicAdd(&cur[p.y & 255], 1);
            ssrc[slot] = p.x;
        }
        __syncthreads();
        for (int r = t; r < items; r += 256) adj[lo + r] = ssrc[r];
    } else {  // overflow fallback (never for this dataset): unstaged writes
        for (int r = lo + t; r < hi; r += 256) {
            int2 p = part[r];
            int slot = atomicAdd(&cur[p.y & 255], 1);
            adj[lo + slot] = p.x;
        }
    }
}

// ---- w_as = W3 @ a3_src, w_ad = W3 @ a3_dst; and W3 padded to stride 244 ---

__global__ void w3a_kernel(const float* __restrict__ W3,
                           const float* __restrict__ a3s,
                           const float* __restrict__ a3d,
                           float* __restrict__ w_as, float* __restrict__ w_ad) {
    int t = threadIdx.x;  // 128 threads
    if (t >= 128) return;
    int k = t & 63;
    const float* a = (t < 64) ? a3s : a3d;
    float s = 0.f;
    for (int c = 0; c < 242; ++c) s = fmaf(W3[k * 242 + c], a[c], s);
    if (t < 64) w_as[k] = s; else w_ad[k] = s;
}

__global__ __launch_bounds__(256)
void w3pad_kernel(const float* __restrict__ W3, float* __restrict__ W3p) {
    int t = blockIdx.x * blockDim.x + threadIdx.x;  // 64*244
    if (t >= 64 * 244) return;
    int k = t / 244, c = t - k * 244;
    W3p[t] = (c < 242) ? W3[k * 242 + c] : 0.f;
}

// ---------------- GEMM + alpha (layers 1 & 2: 64 cols, H=8, C=8) -----------
// Register-blocked, no LDS, 8 nodes per wave (2 per lane). Lane layout:
// jj = lane>>4 picks one of 4 node-pairs, cc = lane&15 picks a 4-col slice.

template <int K>
__global__ __launch_bounds__(256)
void gemm_alpha_v3(const float* __restrict__ X, const float* __restrict__ W,
                   const float* __restrict__ a_src, const float* __restrict__ a_dst,
                   float* __restrict__ XW, float* __restrict__ As, float* __restrict__ Ad,
                   int N) {
    int wave = threadIdx.x >> 6, lane = threadIdx.x & 63;
    int jj = lane >> 4, cc = lane & 15;
    int base = blockIdx.x * 32 + wave * 8 + jj * 2;

    int n0 = (base < N) ? base : N - 1;
    int n1 = (base + 1 < N) ? base + 1 : N - 1;
    const float* x0 = X + (size_t)n0 * K;
    const float* x1 = X + (size_t)n1 * K;

    float4 o0 = make_float4(0.f, 0.f, 0.f, 0.f);
    float4 o1 = make_float4(0.f, 0.f, 0.f, 0.f);

    const float* wp = W + cc * 4;
#pragma unroll 4
    for (int k = 0; k < K; k += 4) {
        float4 w0 = *(const float4*)(wp + (size_t)(k + 0) * 64);
        float4 w1 = *(const float4*)(wp + (size_t)(k + 1) * 64);
        float4 w2 = *(const float4*)(wp + (size_t)(k + 2) * 64);
        float4 w3 = *(const float4*)(wp + (size_t)(k + 3) * 64);
        float4 m0 = *(const float4*)(x0 + k);
        float4 m1 = *(const float4*)(x1 + k);

        o0.x = fmaf(m0.x, w0.x, o0.x);
        o0.y = fmaf(m0.x, w0.y, o0.y);
        o0.z = fmaf(m0.x, w0.z, o0.z);
        o0.w = fmaf(m0.x, w0.w, o0.w);
        o0.x = fmaf(m0.y, w1.x, o0.x);
        o0.y = fmaf(m0.y, w1.y, o0.y);
        o0.z = fmaf(m0.y, w1.z, o0.z);
        o0.w = fmaf(m0.y, w1.w, o0.w);
        o0.x = fmaf(m0.z, w2.x, o0.x);
        o0.y = fmaf(m0.z, w2.y, o0.y);
        o0.z = fmaf(m0.z, w2.z, o0.z);
        o0.w = fmaf(m0.z, w2.w, o0.w);
        o0.x = fmaf(m0.w, w3.x, o0.x);
        o0.y = fmaf(m0.w, w3.y, o0.y);
        o0.z = fmaf(m0.w, w3.z, o0.z);
        o0.w = fmaf(m0.w, w3.w, o0.w);

        o1.x = fmaf(m1.x, w0.x, o1.x);
        o1.y = fmaf(m1.x, w0.y, o1.y);
        o1.z = fmaf(m1.x, w0.z, o1.z);
        o1.w = fmaf(m1.x, w0.w, o1.w);
        o1.x = fmaf(m1.y, w1.x, o1.x);
        o1.y = fmaf(m1.y, w1.y, o1.y);
        o1.z = fmaf(m1.y, w1.z, o1.z);
        o1.w = fmaf(m1.y, w1.w, o1.w);
        o1.x = fmaf(m1.z, w2.x, o1.x);
        o1.y = fmaf(m1.z, w2.y, o1.y);
        o1.z = fmaf(m1.z, w2.z, o1.z);
        o1.w = fmaf(m1.z, w2.w, o1.w);
        o1.x = fmaf(m1.w, w3.x, o1.x);
        o1.y = fmaf(m1.w, w3.y, o1.y);
        o1.z = fmaf(m1.w, w3.z, o1.z);
        o1.w = fmaf(m1.w, w3.w, o1.w);
    }

    float4 av = *(const float4*)(a_src + cc * 4);
    float4 dv = *(const float4*)(a_dst + cc * 4);

    if (base < N) {
        *(float4*)(XW + (size_t)base * 64 + cc * 4) = o0;
        float s = o0.x * av.x + o0.y * av.y + o0.z * av.z + o0.w * av.w;
        float d = o0.x * dv.x + o0.y * dv.y + o0.z * dv.z + o0.w * dv.w;
        s += __shfl_xor(s, 1);
        d += __shfl_xor(d, 1);
        if ((cc & 1) == 0) {
            As[base * 8 + (cc >> 1)] = s;
            Ad[base * 8 + (cc >> 1)] = d;
        }
    }
    if (base + 1 < N) {
        *(float4*)(XW + (size_t)(base + 1) * 64 + cc * 4) = o1;
        float s = o1.x * av.x + o1.y * av.y + o1.z * av.z + o1.w * av.w;
        float d = o1.x * dv.x + o1.y * dv.y + o1.z * dv.z + o1.w * dv.w;
        s += __shfl_xor(s, 1);
        d += __shfl_xor(d, 1);
        if ((cc & 1) == 0) {
            As[(base + 1) * 8 + (cc >> 1)] = s;
            Ad[(base + 1) * 8 + (cc >> 1)] = d;
        }
    }
}

// ---------------- Aggregation (layers 1 & 2): one wave per dst node --------

template <bool WITH_A3>
__global__ __launch_bounds__(256)
void agg_h8c8(const float* __restrict__ XW, const float* __restrict__ As,
              const float* __restrict__ Ad, const int* __restrict__ row_ptr,
              const int* __restrict__ adj, const float* __restrict__ bias,
              float* __restrict__ OUT,
              const float* __restrict__ w_as, const float* __restrict__ w_ad,
              float* __restrict__ As3, float* __restrict__ Ad3, int N) {
    int wave = threadIdx.x >> 6, lane = threadIdx.x & 63;
    int node = blockIdx.x * 4 + wave;
    if (node >= N) return;
    int beg = row_ptr[node], end = row_ptr[node + 1];
    int h = lane >> 3;
    float ad = Ad[node * 8 + h];

    float acc = 0.f, den = 0.f;
    int idx = beg;
    for (; idx + 8 <= end; idx += 8) {
        int s[8];
        float e[8], x[8];
#pragma unroll
        for (int k = 0; k < 8; ++k) s[k] = adj[idx + k];
#pragma unroll
        for (int k = 0; k < 8; ++k) e[k] = As[(size_t)s[k] * 8 + h];
#pragma unroll
        for (int k = 0; k < 8; ++k) x[k] = XW[(size_t)s[k] * 64 + lane];
#pragma unroll
        for (int k = 0; k < 8; ++k) {
            float p = __expf(lrelu(e[k] + ad));
            den += p;
            acc = fmaf(p, x[k], acc);
        }
    }
    for (; idx < end; ++idx) {
        int src = adj[idx];
        float p = __expf(lrelu(As[(size_t)src * 8 + h] + ad));
        den += p;
        acc = fmaf(p, XW[(size_t)src * 64 + lane], acc);
    }

    float v = fmaxf(acc / (den + 1e-16f) + bias[lane], 0.f);
    OUT[(size_t)node * 64 + lane] = v;

    if (WITH_A3) {
        float s3 = v * w_as[lane];
        float d3 = v * w_ad[lane];
#pragma unroll
        for (int m = 1; m <= 32; m <<= 1) {
            s3 += __shfl_xor(s3, m);
            d3 += __shfl_xor(d3, m);
        }
        if (lane == 0) {
            As3[node] = s3;
            Ad3[node] = d3;
        }
    }
}

// ---------------- Layer 3 aggregation in h-space (no LDS) ------------------

__global__ __launch_bounds__(256)
void agg3msg_kernel(const float* __restrict__ H2, const float* __restrict__ As3,
                    const float* __restrict__ Ad3, const int* __restrict__ row_ptr,
                    const int* __restrict__ adj, float* __restrict__ MSG, int N) {
    int wave = threadIdx.x >> 6, lane = threadIdx.x & 63;
    int node = blockIdx.x * 4 + wave;
    if (node >= N) return;
    int beg = row_ptr[node], end = row_ptr[node + 1];
    float ad = Ad3[node];

    float acc = 0.f, den = 0.f;
    int idx = beg;
    for (; idx + 8 <= end; idx += 8) {
        int s[8];
        float e[8], x[8];
#pragma unroll
        for (int k = 0; k < 8; ++k) s[k] = adj[idx + k];
#pragma unroll
        for (int k = 0; k < 8; ++k) e[k] = As3[s[k]];
#pragma unroll
        for (int k = 0; k < 8; ++k) x[k] = H2[(size_t)s[k] * 64 + lane];
#pragma unroll
        for (int k = 0; k < 8; ++k) {
            float p = __expf(lrelu(e[k] + ad));
            den += p;
            acc = fmaf(p, x[k], acc);
        }
    }
    for (; idx < end; ++idx) {
        int src = adj[idx];
        float p = __expf(lrelu(As3[src] + ad));
        den += p;
        acc = fmaf(p, H2[(size_t)src * 64 + lane], acc);
    }
    MSG[(size_t)node * 64 + lane] = acc / (den + 1e-16f);
}

// ---------------- gemm3 v2: OUT = softmax_pairs(relu(MSG @ W3 + b3)) -------

__global__ __launch_bounds__(256)
void gemm3_kernel(const float* __restrict__ MSG, const float* __restrict__ W3p,
                  const float* __restrict__ bias, float* __restrict__ OUT, int N) {
    __shared__ float msh[4][8][64];
    int wave = threadIdx.x >> 6, lane = threadIdx.x & 63;
    int base = blockIdx.x * 32 + wave * 8;

#pragma unroll
    for (int j = 0; j < 8; ++j) {
        int node = base + j;
        msh[wave][j][lane] = (node < N) ? MSG[(size_t)node * 64 + lane] : 0.f;
    }
    // same-wave LDS RAW: DS pipe in-order, compiler inserts lgkmcnt wait

    int c0 = lane * 4;  // lanes 0..60 carry channels; 61-63 idle
    if (c0 < 242) {
        float o[8][4];
#pragma unroll
        for (int j = 0; j < 8; ++j)
#pragma unroll
            for (int q = 0; q < 4; ++q) o[j][q] = 0.f;

#pragma unroll 4
        for (int k = 0; k < 64; k += 4) {
            float4 w0 = *(const float4*)(W3p + (size_t)(k + 0) * 244 + c0);
            float4 w1 = *(const float4*)(W3p + (size_t)(k + 1) * 244 + c0);
            float4 w2 = *(const float4*)(W3p + (size_t)(k + 2) * 244 + c0);
            float4 w3 = *(const float4*)(W3p + (size_t)(k + 3) * 244 + c0);
#pragma unroll
            for (int j = 0; j < 8; ++j) {
                float4 m = *(const float4*)(&msh[wave][j][k]);
                o[j][0] = fmaf(m.x, w0.x, o[j][0]);
                o[j][1] = fmaf(m.x, w0.y, o[j][1]);
                o[j][2] = fmaf(m.x, w0.z, o[j][2]);
                o[j][3] = fmaf(m.x, w0.w, o[j][3]);
                o[j][0] = fmaf(m.y, w1.x, o[j][0]);
                o[j][1] = fmaf(m.y, w1.y, o[j][1]);
                o[j][2] = fmaf(m.y, w1.z, o[j][2]);
                o[j][3] = fmaf(m.y, w1.w, o[j][3]);
                o[j][0] = fmaf(m.z, w2.x, o[j][0]);
                o[j][1] = fmaf(m.z, w2.y, o[j][1]);
                o[j][2] = fmaf(m.z, w2.z, o[j][2]);
                o[j][3] = fmaf(m.z, w2.w, o[j][3]);
                o[j][0] = fmaf(m.w, w3.x, o[j][0]);
                o[j][1] = fmaf(m.w, w3.y, o[j][1]);
                o[j][2] = fmaf(m.w, w3.z, o[j][2]);
                o[j][3] = fmaf(m.w, w3.w, o[j][3]);
            }
        }

        float b0 = bias[c0], b1v = bias[c0 + 1];
        float b2v = (c0 + 2 < 242) ? bias[c0 + 2] : 0.f;
        float b3v = (c0 + 3 < 242) ? bias[c0 + 3] : 0.f;
#pragma unroll
        for (int j = 0; j < 8; ++j) {
            int node = base + j;
            if (node >= N) break;
            size_t out_base = (size_t)node * 242 + c0;
            float v0 = fmaxf(o[j][0] + b0, 0.f);
            float v1 = fmaxf(o[j][1] + b1v, 0.f);
            float m01 = fmaxf(v0, v1);
            float e0 = __expf(v0 - m01), e1 = __expf(v1 - m01);
            float r01 = 1.f / (e0 + e1);
            OUT[out_base]     = e0 * r01;
            OUT[out_base + 1] = e1 * r01;
            if (c0 + 2 < 242) {
                float v2 = fmaxf(o[j][2] + b2v, 0.f);
                float v3 = fmaxf(o[j][3] + b3v, 0.f);
                float m23 = fmaxf(v2, v3);
                float e2 = __expf(v2 - m23), e3 = __expf(v3 - m23);
                float r23 = 1.f / (e2 + e3);
                OUT[out_base + 2] = e2 * r23;
                OUT[out_base + 3] = e3 * r23;
            }
        }
    }
}

// ---------------- launch ----------------

extern "C" void kernel_launch(void* const* d_in, const int* in_sizes, int n_in,
                              void* d_out, int out_size, void* d_ws, size_t ws_size,
                              hipStream_t stream) {
    const float* x   = (const float*)d_in[0];
    const void*  ei  = d_in[1];
    const float* W1  = (const float*)d_in[2];
    const float* a1s = (const float*)d_in[3];
    const float* a1d = (const float*)d_in[4];
    const float* b1  = (const float*)d_in[5];
    const float* W2  = (const float*)d_in[6];
    const float* a2s = (const float*)d_in[7];
    const float* a2d = (const float*)d_in[8];
    const float* b2  = (const float*)d_in[9];
    const float* W3  = (const float*)d_in[10];
    const float* a3s = (const float*)d_in[11];
    const float* a3d = (const float*)d_in[12];
    const float* b3  = (const float*)d_in[13];
    float* out = (float*)d_out;

    const int N = in_sizes[0] / 128;  // 50000
    const int E = in_sizes[1] / 2;    // 800000

    char* w = (char*)d_ws;
    auto alloc = [&](size_t bytes) {
        char* p = w;
        w += (bytes + 255) & ~(size_t)255;
        return p;
    };
    int*   flag    = (int*)alloc(4);
    int*   row_ptr = (int*)alloc(((size_t)N + 1) * 4);
    int*   adj     = (int*)alloc((size_t)(E + N) * 4);
    int*   btot    = (int*)alloc(256 * 4);
    int*   bbase   = (int*)alloc(257 * 4);
    float* As      = (float*)alloc((size_t)N * 8 * 4);
    float* Ad      = (float*)alloc((size_t)N * 8 * 4);
    float* As3     = (float*)alloc((size_t)N * 4);
    float* Ad3     = (float*)alloc((size_t)N * 4);
    float* w_as    = (float*)alloc(64 * 4);
    float* w_ad    = (float*)alloc(64 * 4);
    float* W3p     = (float*)alloc((size_t)64 * 244 * 4);
    float* bufA    = (float*)alloc((size_t)N * 64 * 4);
    float* bufB    = (float*)alloc((size_t)N * 64 * 4);
    // CSR scratch aliased into bufA (12.8MB): part 6.8MB @0, blkhist 256KB @7MB,
    // blkoff 256KB @7.25MB. All dead before gemm_alpha first writes bufA.
    int2*  part    = (int2*)bufA;
    int*   blkhist = (int*)((char*)bufA + (size_t)7 * 1024 * 1024);
    int*   blkoff  = (int*)((char*)bufA + (size_t)7 * 1024 * 1024 + 256 * 1024);

    int tot  = E + N;                       // 850000
    int nblk = (tot + CH - 1) / CH;         // 208 <= 256
    int nb   = (N + 255) >> 8;              // 196 <= 256

    // CSR build (bucketed counting sort; includes self-loops)
    detect_kernel<<<1, 64, 0, stream>>>((const int*)ei, flag);
    zero_btot_kernel<<<1, 256, 0, stream>>>(btot);
    histA_kernel<<<nblk, 256, 0, stream>>>(ei, flag, blkhist, btot, E, N);
    bucket_scan_kernel<<<1, 256, 0, stream>>>(btot, bbase, nb, tot);
    blk_scan_kernel<<<nb, 256, 0, stream>>>(blkhist, bbase, blkoff, nblk);
    partC_kernel<<<nblk, 256, 0, stream>>>(ei, flag, blkoff, part, E, N);
    csrD_kernel<<<nb, 256, 0, stream>>>(part, bbase, row_ptr, adj, N);
    w3a_kernel<<<1, 128, 0, stream>>>(W3, a3s, a3d, w_as, w_ad);
    w3pad_kernel<<<(64 * 244 + 255) / 256, 256, 0, stream>>>(W3, W3p);

    int nb4 = (N + 3) / 4;
    int nb32 = (N + 31) / 32;

    // Layer 1: x -> bufA (xw1), agg -> bufB (h1)
    gemm_alpha_v3<128><<<nb32, 256, 0, stream>>>(x, W1, a1s, a1d, bufA, As, Ad, N);
    agg_h8c8<false><<<nb4, 256, 0, stream>>>(bufA, As, Ad, row_ptr, adj, b1, bufB,
                                             nullptr, nullptr, nullptr, nullptr, N);
    // Layer 2: bufB -> bufB in-place (xw2), agg -> bufA (h2) + As3/Ad3 epilogue
    gemm_alpha_v3<64><<<nb32, 256, 0, stream>>>(bufB, W2, a2s, a2d, bufB, As, Ad, N);
    agg_h8c8<true><<<nb4, 256, 0, stream>>>(bufB, As, Ad, row_ptr, adj, b2, bufA,
                                            w_as, w_ad, As3, Ad3, N);
    // Layer 3: h-space aggregation (bufA -> bufB), then gemm3 v2 -> out
    agg3msg_kernel<<<nb4, 256, 0, stream>>>(bufA, As3, Ad3, row_ptr, adj, bufB, N);
    gemm3_kernel<<<nb32, 256, 0, stream>>>(bufB, W3p, b3, out, N);
}

// Round 5
// 372.060 us; speedup vs baseline: 1.2531x; 1.0363x over previous
//
#include <hip/hip_runtime.h>
#include <hip/hip_bf16.h>

// GAT 3-layer (PPI-style) on MI355X. fp32 tensors; edge_index (2,E) planar,
// int32/int64 via device flag. R13 -> R14:
// gemm_alpha_v3 was load-latency bound (VGPR_Count=32 -> ~4 loads in flight;
// per-quad global X broadcasts miss L2 (~400cyc); VALUBusy 12%). v4 = gemm3
// structure: block stages its 32 X-rows in LDS (coalesced float4, in-place
// safe), inner loop reads X via LDS broadcast (pad K+4 -> jj-group addrs hit
// banks {0,8,16,24}, conflict-free); only 4 L1/L2-hot W float4 loads remain
// in VMEM per k-quad, feeding 32 FMAs.

#define CH 4096     // items per partition block
#define CAP 8192    // csrD staging capacity (mean bucket = 4352, 60 sigma headroom)

__device__ __forceinline__ float lrelu(float s) { return (s >= 0.f) ? s : 0.2f * s; }

// ---------------- edge dtype detection: (2,E) planar ----------------

__global__ void detect_kernel(const int* __restrict__ ei, int* __restrict__ flag) {
    int t = threadIdx.x;  // 64 lanes
    int v = ei[2 * t + 1];
    unsigned long long b = __ballot(v == 0);
    if (t == 0) *flag = (b == ~0ULL) ? 1 : 0;
}

__device__ __forceinline__ int edge_at(const void* ei, int is64, long long idx) {
    return is64 ? (int)((const long long*)ei)[idx] : ((const int*)ei)[idx];
}

// ---------------- bucketed CSR build ----------------

__global__ void zero_btot_kernel(int* __restrict__ btot) {
    btot[threadIdx.x] = 0;  // 256 threads
}

// Per-block bucket histogram. Item t in [0,E) = edge t (dst row), [E,E+N) =
// self-loop (dst = t-E). blkhist[bucket*256 + blk], btot[bucket].
__global__ __launch_bounds__(256)
void histA_kernel(const void* __restrict__ ei, const int* __restrict__ flag,
                  int* __restrict__ blkhist, int* __restrict__ btot, int E, int N) {
    __shared__ int h[256];
    int t = threadIdx.x;
    h[t] = 0;
    __syncthreads();
    int is64 = *flag;
    long long base = (long long)blockIdx.x * CH;
    long long tot = (long long)E + N;
#pragma unroll
    for (int i = 0; i < CH / 256; ++i) {
        long long idx = base + t + i * 256;
        if (idx < tot) {
            int dst = (idx < E) ? edge_at(ei, is64, (long long)E + idx) : (int)(idx - E);
            atomicAdd(&h[(dst >> 8) & 255], 1);
        }
    }
    __syncthreads();
    int nb = (N + 255) >> 8;
    if (t < nb) {
        blkhist[t * 256 + blockIdx.x] = h[t];
        atomicAdd(&btot[t], h[t]);
    }
}

// Exclusive scan over bucket totals -> bbase[0..nb], bbase[nb] = total.
__global__ __launch_bounds__(256)
void bucket_scan_kernel(const int* __restrict__ btot, int* __restrict__ bbase,
                        int nb, int total) {
    __shared__ int s[256];
    int t = threadIdx.x;
    int v = (t < nb) ? btot[t] : 0;
    s[t] = v;
    __syncthreads();
#pragma unroll
    for (int off = 1; off < 256; off <<= 1) {
        int u = (t >= off) ? s[t - off] : 0;
        __syncthreads();
        s[t] += u;
        __syncthreads();
    }
    if (t < nb) bbase[t] = s[t] - v;
    if (t == 0) bbase[nb] = total;
}

// Per-bucket exclusive scan across blocks -> absolute run base blkoff.
__global__ __launch_bounds__(256)
void blk_scan_kernel(const int* __restrict__ blkhist, const int* __restrict__ bbase,
                     int* __restrict__ blkoff, int nblk) {
    __shared__ int s[256];
    int t = threadIdx.x;
    int b = blockIdx.x;
    int v = (t < nblk) ? blkhist[b * 256 + t] : 0;
    s[t] = v;
    __syncthreads();
#pragma unroll
    for (int off = 1; off < 256; off <<= 1) {
        int u = (t >= off) ? s[t - off] : 0;
        __syncthreads();
        s[t] += u;
        __syncthreads();
    }
    if (t < nblk) blkoff[b * 256 + t] = bbase[b] + s[t] - v;
}

// Partition: stage the block's CH items in LDS sorted by bucket, then write
// each bucket run contiguously (consecutive lanes -> consecutive addresses).
__global__ __launch_bounds__(256)
void partC_kernel(const void* __restrict__ ei, const int* __restrict__ flag,
                  const int* __restrict__ blkoff, int2* __restrict__ part,
                  int E, int N) {
    __shared__ int h[256];
    __shared__ int lst[256];
    __shared__ int cur[256];
    __shared__ int grb[256];
    __shared__ int ssrc[CH];
    __shared__ int sdst[CH];
    int t = threadIdx.x;
    h[t] = 0;
    __syncthreads();
    int is64 = *flag;
    long long base = (long long)blockIdx.x * CH;
    long long tot = (long long)E + N;
    int msrc[CH / 256], mdst[CH / 256], mb[CH / 256];
#pragma unroll
    for (int i = 0; i < CH / 256; ++i) {
        long long idx = base + t + i * 256;
        if (idx < tot) {
            int s, d;
            if (idx < E) {
                s = edge_at(ei, is64, idx);
                d = edge_at(ei, is64, (long long)E + idx);
            } else {
                s = (int)(idx - E);
                d = s;
            }
            msrc[i] = s;
            mdst[i] = d;
            mb[i] = (d >> 8) & 255;
            atomicAdd(&h[mb[i]], 1);
        } else {
            mb[i] = -1;
        }
    }
    __syncthreads();
    // exclusive scan of h -> lst; cur = lst; grb = absolute run base
    int v = h[t];
    lst[t] = v;
    __syncthreads();
#pragma unroll
    for (int off = 1; off < 256; off <<= 1) {
        int u = (t >= off) ? lst[t - off] : 0;
        __syncthreads();
        lst[t] += u;
        __syncthreads();
    }
    int ex = lst[t] - v;   // each thread touches only its own slot here
    lst[t] = ex;
    cur[t] = ex;
    int nb = (N + 255) >> 8;
    grb[t] = (t < nb) ? blkoff[t * 256 + blockIdx.x] : 0;
    __syncthreads();
#pragma unroll
    for (int i = 0; i < CH / 256; ++i) {
        if (mb[i] >= 0) {
            int slot = atomicAdd(&cur[mb[i]], 1);
            ssrc[slot] = msrc[i];
            sdst[slot] = mdst[i];
        }
    }
    __syncthreads();
    int items = (int)((tot - base < CH) ? (tot - base) : CH);
    for (int r = t; r < items; r += 256) {
        int d = sdst[r];
        int b = (d >> 8) & 255;
        part[grb[b] + (r - lst[b])] = make_int2(ssrc[r], d);
    }
}

// Per-bucket local CSR: counts -> scan -> row_ptr; stage srcs in final order
// in LDS; write the bucket's adj region as one contiguous stream.
__global__ __launch_bounds__(256)
void csrD_kernel(const int2* __restrict__ part, const int* __restrict__ bbase,
                 int* __restrict__ row_ptr, int* __restrict__ adj, int N) {
    __shared__ int cnt[256];
    __shared__ int lst[256];
    __shared__ int cur[256];
    __shared__ int ssrc[CAP];
    int t = threadIdx.x;
    int b = blockIdx.x;
    int lo = bbase[b], hi = bbase[b + 1];
    int n0 = b << 8;
    cnt[t] = 0;
    __syncthreads();
    for (int r = lo + t; r < hi; r += 256) atomicAdd(&cnt[part[r].y & 255], 1);
    __syncthreads();
    int v = cnt[t];
    lst[t] = v;
    __syncthreads();
#pragma unroll
    for (int off = 1; off < 256; off <<= 1) {
        int u = (t >= off) ? lst[t - off] : 0;
        __syncthreads();
        lst[t] += u;
        __syncthreads();
    }
    int ex = lst[t] - v;
    lst[t] = ex;
    cur[t] = ex;
    __syncthreads();
    if (n0 + t < N) row_ptr[n0 + t] = lo + ex;
    if (b == gridDim.x - 1 && t == 0) row_ptr[N] = hi;
    int items = hi - lo;
    if (items <= CAP) {
        for (int r = lo + t; r < hi; r += 256) {
            int2 p = part[r];
            int slot = atomicAdd(&cur[p.y & 255], 1);
            ssrc[slot] = p.x;
        }
        __syncthreads();
        for (int r = t; r < items; r += 256) adj[lo + r] = ssrc[r];
    } else {  // overflow fallback (never for this dataset): unstaged writes
        for (int r = lo + t; r < hi; r += 256) {
            int2 p = part[r];
            int slot = atomicAdd(&cur[p.y & 255], 1);
            adj[lo + slot] = p.x;
        }
    }
}

// ---- w_as = W3 @ a3_src, w_ad = W3 @ a3_dst; and W3 padded to stride 244 ---

__global__ void w3a_kernel(const float* __restrict__ W3,
                           const float* __restrict__ a3s,
                           const float* __restrict__ a3d,
                           float* __restrict__ w_as, float* __restrict__ w_ad) {
    int t = threadIdx.x;  // 128 threads
    if (t >= 128) return;
    int k = t & 63;
    const float* a = (t < 64) ? a3s : a3d;
    float s = 0.f;
    for (int c = 0; c < 242; ++c) s = fmaf(W3[k * 242 + c], a[c], s);
    if (t < 64) w_as[k] = s; else w_ad[k] = s;
}

__global__ __launch_bounds__(256)
void w3pad_kernel(const float* __restrict__ W3, float* __restrict__ W3p) {
    int t = blockIdx.x * blockDim.x + threadIdx.x;  // 64*244
    if (t >= 64 * 244) return;
    int k = t / 244, c = t - k * 244;
    W3p[t] = (c < 242) ? W3[k * 242 + c] : 0.f;
}

// ---------------- GEMM + alpha (layers 1 & 2: 64 cols, H=8, C=8) -----------
// v4: 32 nodes per block staged in LDS (coalesced float4; pad row to K+4 so
// the 4 jj-group broadcast reads hit banks {0,8,16,24} -> conflict-free).
// Lane layout: jj = lane>>4 picks a node pair, cc = lane&15 a 4-col slice.
// Per k-quad: 4 coalesced W float4 (L1/L2-hot) + 2 LDS-broadcast float4 feed
// 32 FMAs. In-place safe (X==XW): block reads only rows [32b,32b+32) during
// staging (pre-sync), writes only those rows after.

template <int K>
__global__ __launch_bounds__(256)
void gemm_alpha_v4(const float* __restrict__ X, const float* __restrict__ W,
                   const float* __restrict__ a_src, const float* __restrict__ a_dst,
                   float* __restrict__ XW, float* __restrict__ As, float* __restrict__ Ad,
                   int N) {
    constexpr int S = K + 4;        // padded LDS row stride (floats)
    constexpr int F4R = K / 4;      // float4 per row
    __shared__ float xs[32][S];
    int t = threadIdx.x;
    int block0 = blockIdx.x * 32;

    for (int i = t; i < 32 * F4R; i += 256) {
        int row = i / F4R, c4 = i - row * F4R;
        int node = block0 + row;
        float4 v = (node < N) ? *(const float4*)(X + (size_t)node * K + c4 * 4)
                              : make_float4(0.f, 0.f, 0.f, 0.f);
        *(float4*)(&xs[row][c4 * 4]) = v;
    }
    __syncthreads();

    int wave = t >> 6, lane = t & 63;
    int jj = lane >> 4, cc = lane & 15;
    int r0 = wave * 8 + jj * 2;     // local node pair
    int base = block0 + r0;

    float4 o0 = make_float4(0.f, 0.f, 0.f, 0.f);
    float4 o1 = make_float4(0.f, 0.f, 0.f, 0.f);

    const float* wp = W + cc * 4;
#pragma unroll 2
    for (int k = 0; k < K; k += 4) {
        float4 w0 = *(const float4*)(wp + (size_t)(k + 0) * 64);
        float4 w1 = *(const float4*)(wp + (size_t)(k + 1) * 64);
        float4 w2 = *(const float4*)(wp + (size_t)(k + 2) * 64);
        float4 w3 = *(const float4*)(wp + (size_t)(k + 3) * 64);
        float4 m0 = *(const float4*)(&xs[r0][k]);
        float4 m1 = *(const float4*)(&xs[r0 + 1][k]);

        o0.x = fmaf(m0.x, w0.x, o0.x);
        o0.y = fmaf(m0.x, w0.y, o0.y);
        o0.z = fmaf(m0.x, w0.z, o0.z);
        o0.w = fmaf(m0.x, w0.w, o0.w);
        o0.x = fmaf(m0.y, w1.x, o0.x);
        o0.y = fmaf(m0.y, w1.y, o0.y);
        o0.z = fmaf(m0.y, w1.z, o0.z);
        o0.w = fmaf(m0.y, w1.w, o0.w);
        o0.x = fmaf(m0.z, w2.x, o0.x);
        o0.y = fmaf(m0.z, w2.y, o0.y);
        o0.z = fmaf(m0.z, w2.z, o0.z);
        o0.w = fmaf(m0.z, w2.w, o0.w);
        o0.x = fmaf(m0.w, w3.x, o0.x);
        o0.y = fmaf(m0.w, w3.y, o0.y);
        o0.z = fmaf(m0.w, w3.z, o0.z);
        o0.w = fmaf(m0.w, w3.w, o0.w);

        o1.x = fmaf(m1.x, w0.x, o1.x);
        o1.y = fmaf(m1.x, w0.y, o1.y);
        o1.z = fmaf(m1.x, w0.z, o1.z);
        o1.w = fmaf(m1.x, w0.w, o1.w);
        o1.x = fmaf(m1.y, w1.x, o1.x);
        o1.y = fmaf(m1.y, w1.y, o1.y);
        o1.z = fmaf(m1.y, w1.z, o1.z);
        o1.w = fmaf(m1.y, w1.w, o1.w);
        o1.x = fmaf(m1.z, w2.x, o1.x);
        o1.y = fmaf(m1.z, w2.y, o1.y);
        o1.z = fmaf(m1.z, w2.z, o1.z);
        o1.w = fmaf(m1.z, w2.w, o1.w);
        o1.x = fmaf(m1.w, w3.x, o1.x);
        o1.y = fmaf(m1.w, w3.y, o1.y);
        o1.z = fmaf(m1.w, w3.z, o1.z);
        o1.w = fmaf(m1.w, w3.w, o1.w);
    }

    // epilogue: store xw + per-head alpha partials. Lane's 4 cols sit inside
    // head h = cc>>1; pair-reduce (cc even/odd) covers the 8 cols of the head.
    float4 av = *(const float4*)(a_src + cc * 4);
    float4 dv = *(const float4*)(a_dst + cc * 4);

    if (base < N) {
        *(float4*)(XW + (size_t)base * 64 + cc * 4) = o0;
        float s = o0.x * av.x + o0.y * av.y + o0.z * av.z + o0.w * av.w;
        float d = o0.x * dv.x + o0.y * dv.y + o0.z * dv.z + o0.w * dv.w;
        s += __shfl_xor(s, 1);
        d += __shfl_xor(d, 1);
        if ((cc & 1) == 0) {
            As[base * 8 + (cc >> 1)] = s;
            Ad[base * 8 + (cc >> 1)] = d;
        }
    }
    if (base + 1 < N) {
        *(float4*)(XW + (size_t)(base + 1) * 64 + cc * 4) = o1;
        float s = o1.x * av.x + o1.y * av.y + o1.z * av.z + o1.w * av.w;
        float d = o1.x * dv.x + o1.y * dv.y + o1.z * dv.z + o1.w * dv.w;
        s += __shfl_xor(s, 1);
        d += __shfl_xor(d, 1);
        if ((cc & 1) == 0) {
            As[(base + 1) * 8 + (cc >> 1)] = s;
            Ad[(base + 1) * 8 + (cc >> 1)] = d;
        }
    }
}

// ---------------- Aggregation (layers 1 & 2): one wave per dst node --------

template <bool WITH_A3>
__global__ __launch_bounds__(256)
void agg_h8c8(const float* __restrict__ XW, const float* __restrict__ As,
              const float* __restrict__ Ad, const int* __restrict__ row_ptr,
              const int* __restrict__ adj, const float* __restrict__ bias,
              float* __restrict__ OUT,
              const float* __restrict__ w_as, const float* __restrict__ w_ad,
              float* __restrict__ As3, float* __restrict__ Ad3, int N) {
    int wave = threadIdx.x >> 6, lane = threadIdx.x & 63;
    int node = blockIdx.x * 4 + wave;
    if (node >= N) return;
    int beg = row_ptr[node], end = row_ptr[node + 1];
    int h = lane >> 3;
    float ad = Ad[node * 8 + h];

    float acc = 0.f, den = 0.f;
    int idx = beg;
    for (; idx + 8 <= end; idx += 8) {
        int s[8];
        float e[8], x[8];
#pragma unroll
        for (int k = 0; k < 8; ++k) s[k] = adj[idx + k];
#pragma unroll
        for (int k = 0; k < 8; ++k) e[k] = As[(size_t)s[k] * 8 + h];
#pragma unroll
        for (int k = 0; k < 8; ++k) x[k] = XW[(size_t)s[k] * 64 + lane];
#pragma unroll
        for (int k = 0; k < 8; ++k) {
            float p = __expf(lrelu(e[k] + ad));
            den += p;
            acc = fmaf(p, x[k], acc);
        }
    }
    for (; idx < end; ++idx) {
        int src = adj[idx];
        float p = __expf(lrelu(As[(size_t)src * 8 + h] + ad));
        den += p;
        acc = fmaf(p, XW[(size_t)src * 64 + lane], acc);
    }

    float v = fmaxf(acc / (den + 1e-16f) + bias[lane], 0.f);
    OUT[(size_t)node * 64 + lane] = v;

    if (WITH_A3) {
        float s3 = v * w_as[lane];
        float d3 = v * w_ad[lane];
#pragma unroll
        for (int m = 1; m <= 32; m <<= 1) {
            s3 += __shfl_xor(s3, m);
            d3 += __shfl_xor(d3, m);
        }
        if (lane == 0) {
            As3[node] = s3;
            Ad3[node] = d3;
        }
    }
}

// ---------------- Layer 3 aggregation in h-space (no LDS) ------------------

__global__ __launch_bounds__(256)
void agg3msg_kernel(const float* __restrict__ H2, const float* __restrict__ As3,
                    const float* __restrict__ Ad3, const int* __restrict__ row_ptr,
                    const int* __restrict__ adj, float* __restrict__ MSG, int N) {
    int wave = threadIdx.x >> 6, lane = threadIdx.x & 63;
    int node = blockIdx.x * 4 + wave;
    if (node >= N) return;
    int beg = row_ptr[node], end = row_ptr[node + 1];
    float ad = Ad3[node];

    float acc = 0.f, den = 0.f;
    int idx = beg;
    for (; idx + 8 <= end; idx += 8) {
        int s[8];
        float e[8], x[8];
#pragma unroll
        for (int k = 0; k < 8; ++k) s[k] = adj[idx + k];
#pragma unroll
        for (int k = 0; k < 8; ++k) e[k] = As3[s[k]];
#pragma unroll
        for (int k = 0; k < 8; ++k) x[k] = H2[(size_t)s[k] * 64 + lane];
#pragma unroll
        for (int k = 0; k < 8; ++k) {
            float p = __expf(lrelu(e[k] + ad));
            den += p;
            acc = fmaf(p, x[k], acc);
        }
    }
    for (; idx < end; ++idx) {
        int src = adj[idx];
        float p = __expf(lrelu(As3[src] + ad));
        den += p;
        acc = fmaf(p, H2[(size_t)src * 64 + lane], acc);
    }
    MSG[(size_t)node * 64 + lane] = acc / (den + 1e-16f);
}

// ---------------- gemm3 v2: OUT = softmax_pairs(relu(MSG @ W3 + b3)) -------

__global__ __launch_bounds__(256)
void gemm3_kernel(const float* __restrict__ MSG, const float* __restrict__ W3p,
                  const float* __restrict__ bias, float* __restrict__ OUT, int N) {
    __shared__ float msh[4][8][64];
    int wave = threadIdx.x >> 6, lane = threadIdx.x & 63;
    int base = blockIdx.x * 32 + wave * 8;

#pragma unroll
    for (int j = 0; j < 8; ++j) {
        int node = base + j;
        msh[wave][j][lane] = (node < N) ? MSG[(size_t)node * 64 + lane] : 0.f;
    }
    // same-wave LDS RAW: DS pipe in-order, compiler inserts lgkmcnt wait

    int c0 = lane * 4;  // lanes 0..60 carry channels; 61-63 idle
    if (c0 < 242) {
        float o[8][4];
#pragma unroll
        for (int j = 0; j < 8; ++j)
#pragma unroll
            for (int q = 0; q < 4; ++q) o[j][q] = 0.f;

#pragma unroll 4
        for (int k = 0; k < 64; k += 4) {
            float4 w0 = *(const float4*)(W3p + (size_t)(k + 0) * 244 + c0);
            float4 w1 = *(const float4*)(W3p + (size_t)(k + 1) * 244 + c0);
            float4 w2 = *(const float4*)(W3p + (size_t)(k + 2) * 244 + c0);
            float4 w3 = *(const float4*)(W3p + (size_t)(k + 3) * 244 + c0);
#pragma unroll
            for (int j = 0; j < 8; ++j) {
                float4 m = *(const float4*)(&msh[wave][j][k]);
                o[j][0] = fmaf(m.x, w0.x, o[j][0]);
                o[j][1] = fmaf(m.x, w0.y, o[j][1]);
                o[j][2] = fmaf(m.x, w0.z, o[j][2]);
                o[j][3] = fmaf(m.x, w0.w, o[j][3]);
                o[j][0] = fmaf(m.y, w1.x, o[j][0]);
                o[j][1] = fmaf(m.y, w1.y, o[j][1]);
                o[j][2] = fmaf(m.y, w1.z, o[j][2]);
                o[j][3] = fmaf(m.y, w1.w, o[j][3]);
                o[j][0] = fmaf(m.z, w2.x, o[j][0]);
                o[j][1] = fmaf(m.z, w2.y, o[j][1]);
                o[j][2] = fmaf(m.z, w2.z, o[j][2]);
                o[j][3] = fmaf(m.z, w2.w, o[j][3]);
                o[j][0] = fmaf(m.w, w3.x, o[j][0]);
                o[j][1] = fmaf(m.w, w3.y, o[j][1]);
                o[j][2] = fmaf(m.w, w3.z, o[j][2]);
                o[j][3] = fmaf(m.w, w3.w, o[j][3]);
            }
        }

        float b0 = bias[c0], b1v = bias[c0 + 1];
        float b2v = (c0 + 2 < 242) ? bias[c0 + 2] : 0.f;
        float b3v = (c0 + 3 < 242) ? bias[c0 + 3] : 0.f;
#pragma unroll
        for (int j = 0; j < 8; ++j) {
            int node = base + j;
            if (node >= N) break;
            size_t out_base = (size_t)node * 242 + c0;
            float v0 = fmaxf(o[j][0] + b0, 0.f);
            float v1 = fmaxf(o[j][1] + b1v, 0.f);
            float m01 = fmaxf(v0, v1);
            float e0 = __expf(v0 - m01), e1 = __expf(v1 - m01);
            float r01 = 1.f / (e0 + e1);
            OUT[out_base]     = e0 * r01;
            OUT[out_base + 1] = e1 * r01;
            if (c0 + 2 < 242) {
                float v2 = fmaxf(o[j][2] + b2v, 0.f);
                float v3 = fmaxf(o[j][3] + b3v, 0.f);
                float m23 = fmaxf(v2, v3);
                float e2 = __expf(v2 - m23), e3 = __expf(v3 - m23);
                float r23 = 1.f / (e2 + e3);
                OUT[out_base + 2] = e2 * r23;
                OUT[out_base + 3] = e3 * r23;
            }
        }
    }
}

// ---------------- launch ----------------

extern "C" void kernel_launch(void* const* d_in, const int* in_sizes, int n_in,
                              void* d_out, int out_size, void* d_ws, size_t ws_size,
                              hipStream_t stream) {
    const float* x   = (const float*)d_in[0];
    const void*  ei  = d_in[1];
    const float* W1  = (const float*)d_in[2];
    const float* a1s = (const float*)d_in[3];
    const float* a1d = (const float*)d_in[4];
    const float* b1  = (const float*)d_in[5];
    const float* W2  = (const float*)d_in[6];
    const float* a2s = (const float*)d_in[7];
    const float* a2d = (const float*)d_in[8];
    const float* b2  = (const float*)d_in[9];
    const float* W3  = (const float*)d_in[10];
    const float* a3s = (const float*)d_in[11];
    const float* a3d = (const float*)d_in[12];
    const float* b3  = (const float*)d_in[13];
    float* out = (float*)d_out;

    const int N = in_sizes[0] / 128;  // 50000
    const int E = in_sizes[1] / 2;    // 800000

    char* w = (char*)d_ws;
    auto alloc = [&](size_t bytes) {
        char* p = w;
        w += (bytes + 255) & ~(size_t)255;
        return p;
    };
    int*   flag    = (int*)alloc(4);
    int*   row_ptr = (int*)alloc(((size_t)N + 1) * 4);
    int*   adj     = (int*)alloc((size_t)(E + N) * 4);
    int*   btot    = (int*)alloc(256 * 4);
    int*   bbase   = (int*)alloc(257 * 4);
    float* As      = (float*)alloc((size_t)N * 8 * 4);
    float* Ad      = (float*)alloc((size_t)N * 8 * 4);
    float* As3     = (float*)alloc((size_t)N * 4);
    float* Ad3     = (float*)alloc((size_t)N * 4);
    float* w_as    = (float*)alloc(64 * 4);
    float* w_ad    = (float*)alloc(64 * 4);
    float* W3p     = (float*)alloc((size_t)64 * 244 * 4);
    float* bufA    = (float*)alloc((size_t)N * 64 * 4);
    float* bufB    = (float*)alloc((size_t)N * 64 * 4);
    // CSR scratch aliased into bufA (12.8MB): part 6.8MB @0, blkhist 256KB @7MB,
    // blkoff 256KB @7.25MB. All dead before gemm_alpha first writes bufA.
    int2*  part    = (int2*)bufA;
    int*   blkhist = (int*)((char*)bufA + (size_t)7 * 1024 * 1024);
    int*   blkoff  = (int*)((char*)bufA + (size_t)7 * 1024 * 1024 + 256 * 1024);

    int tot  = E + N;                       // 850000
    int nblk = (tot + CH - 1) / CH;         // 208 <= 256
    int nb   = (N + 255) >> 8;              // 196 <= 256

    // CSR build (bucketed counting sort; includes self-loops)
    detect_kernel<<<1, 64, 0, stream>>>((const int*)ei, flag);
    zero_btot_kernel<<<1, 256, 0, stream>>>(btot);
    histA_kernel<<<nblk, 256, 0, stream>>>(ei, flag, blkhist, btot, E, N);
    bucket_scan_kernel<<<1, 256, 0, stream>>>(btot, bbase, nb, tot);
    blk_scan_kernel<<<nb, 256, 0, stream>>>(blkhist, bbase, blkoff, nblk);
    partC_kernel<<<nblk, 256, 0, stream>>>(ei, flag, blkoff, part, E, N);
    csrD_kernel<<<nb, 256, 0, stream>>>(part, bbase, row_ptr, adj, N);
    w3a_kernel<<<1, 128, 0, stream>>>(W3, a3s, a3d, w_as, w_ad);
    w3pad_kernel<<<(64 * 244 + 255) / 256, 256, 0, stream>>>(W3, W3p);

    int nb4 = (N + 3) / 4;
    int nb32 = (N + 31) / 32;

    // Layer 1: x -> bufA (xw1), agg -> bufB (h1)
    gemm_alpha_v4<128><<<nb32, 256, 0, stream>>>(x, W1, a1s, a1d, bufA, As, Ad, N);
    agg_h8c8<false><<<nb4, 256, 0, stream>>>(bufA, As, Ad, row_ptr, adj, b1, bufB,
                                             nullptr, nullptr, nullptr, nullptr, N);
    // Layer 2: bufB -> bufB in-place (xw2), agg -> bufA (h2) + As3/Ad3 epilogue
    gemm_alpha_v4<64><<<nb32, 256, 0, stream>>>(bufB, W2, a2s, a2d, bufB, As, Ad, N);
    agg_h8c8<true><<<nb4, 256, 0, stream>>>(bufB, As, Ad, row_ptr, adj, b2, bufA,
                                            w_as, w_ad, As3, Ad3, N);
    // Layer 3: h-space aggregation (bufA -> bufB), then gemm3 v2 -> out
    agg3msg_kernel<<<nb4, 256, 0, stream>>>(bufA, As3, Ad3, row_ptr, adj, bufB, N);
    gemm3_kernel<<<nb32, 256, 0, stream>>>(bufB, W3p, b3, out, N);
}